// Round 20
// baseline (153.545 us; speedup 1.0000x reference)
//
#include <hip/hip_runtime.h>
#include <hip/hip_bf16.h>

#define B_ 8
#define SPREV 4095
#define S_ 4096
#define E_ 2048
#define H_ 16
#define HD_ 128
#define LOW_ 512
#define NCH 64      // attention s-chunks per batch
#define CHK 64      // positions per chunk
#define L2INV 0.207620506f   // log2(10000)/64

typedef short s8v __attribute__((ext_vector_type(8)));
typedef float f4v __attribute__((ext_vector_type(4)));

__device__ __forceinline__ short f2bf_s(float f) {
  return (short)__bfloat16_as_ushort(__float2bfloat16(f));
}
__device__ __forceinline__ float bf2f(unsigned short h) {
  union { unsigned u; float f; } v; v.u = ((unsigned)h) << 16;
  return v.f;
}
// DCE sinks (rule 17): keep loaded registers live without cost.
__device__ __forceinline__ void sink_f4(f4v v) {
  asm volatile("" :: "v"(v[0]), "v"(v[1]), "v"(v[2]), "v"(v[3]));
}
__device__ __forceinline__ void sink_s8(s8v v) {
  union { s8v s; int i[4]; } u; u.s = v;
  asm volatile("" :: "v"(u.i[0]), "v"(u.i[1]), "v"(u.i[2]), "v"(u.i[3]));
}

// Zero all accumulation targets (55296 ws floats + 16384 out floats).
__global__ __launch_bounds__(256) void init_kernel(float* __restrict__ ws_pre,
                                                   float* __restrict__ out) {
  int i = blockIdx.x * 256 + threadIdx.x;
  if (i < 55296) ws_pre[i] = 0.f;           // Cq,Qc,qr_pre,ckvn,krn,o_heads
  else if (i < 71680) out[i - 55296] = 0.f;
}

// out[b][n] += sum_k x[b][k] * W[k][n], k in [k0, k0+32).
__global__ __launch_bounds__(128) void matvec8(
    const float* __restrict__ x, int K,
    const float* __restrict__ W0, int N0, float* __restrict__ o0,
    const float* __restrict__ W1, int N1, float* __restrict__ o1,
    const float* __restrict__ W2, int N2, float* __restrict__ o2)
{
  int cb = blockIdx.x;
  int nb0 = N0 >> 7, nb1 = N1 >> 7;
  const float* W; float* o; int N, colbase;
  if (cb < nb0)            { W = W0; o = o0; N = N0; colbase = cb << 7; }
  else if (cb < nb0 + nb1) { W = W1; o = o1; N = N1; colbase = (cb - nb0) << 7; }
  else                     { W = W2; o = o2; N = N2; colbase = (cb - nb0 - nb1) << 7; }
  int col = colbase + threadIdx.x;
  int k0 = blockIdx.y * 32;
  float acc[B_];
  #pragma unroll
  for (int b = 0; b < B_; ++b) acc[b] = 0.f;
  const float* Wp = W + (size_t)k0 * N + col;
  #pragma unroll 8
  for (int k = 0; k < 32; ++k) {
    float wv = Wp[(size_t)k * N];
    #pragma unroll
    for (int b = 0; b < B_; ++b)
      acc[b] = fmaf(x[b * K + k0 + k], wv, acc[b]);   // uniform -> s_load
  }
  #pragma unroll
  for (int b = 0; b < B_; ++b) atomicAdd(&o[b * N + col], acc[b]);
}

// qeff[b,h,l] = sum_d FU[l, h*128+d] * Qc[b, h*128+d]; grid (64, 8) x 256.
__global__ __launch_bounds__(256) void qeff_kernel(
    const float* __restrict__ Qc, const float* __restrict__ FU,
    unsigned short* __restrict__ qeff)
{
  int bx = blockIdx.x, b = blockIdx.y, t = threadIdx.x;
  int h = bx >> 2, lq = bx & 3;
  int g = t >> 4, li = t & 15;
  __shared__ float qs[HD_];
  if (t < 128) qs[t] = Qc[b * E_ + h * HD_ + t];
  __syncthreads();
  f4v q0 = *(const f4v*)&qs[li * 8];
  f4v q1 = *(const f4v*)&qs[li * 8 + 4];
  #pragma unroll 2
  for (int p = 0; p < 8; ++p) {
    int l = lq * 128 + p * 16 + g;
    const f4v* w4 = (const f4v*)(FU + (size_t)l * (2 * E_) + h * HD_ + li * 8);
    f4v w0 = w4[0], w1 = w4[1];
    float a = w0[0]*q0[0] + w0[1]*q0[1] + w0[2]*q0[2] + w0[3]*q0[3]
            + w1[0]*q1[0] + w1[1]*q1[1] + w1[2]*q1[2] + w1[3]*q1[3];
    a += __shfl_xor(a, 1); a += __shfl_xor(a, 2);
    a += __shfl_xor(a, 4); a += __shfl_xor(a, 8);
    if (li == 0) qeff[(size_t)(b * H_ + h) * LOW_ + l] = (unsigned short)f2bf_s(a);
  }
}

// Flash-decode ablation template. MODE: 0=full(real), 1=loads-only,
// 2=A+B only, 3=C only (fake P), 4=full minus final stores.
template<int MODE>
__global__ __launch_bounds__(512) void attn_kernel(
    const float* __restrict__ ckv_cache, const float* __restrict__ ckv_new,
    const unsigned short* __restrict__ qeff,
    const float* __restrict__ kr_cache, const float* __restrict__ kr_new,
    const float* __restrict__ qr_pre,
    unsigned short* __restrict__ acc_part, float* __restrict__ m_part,
    float* __restrict__ l_part)
{
  int chunk = blockIdx.x, b = blockIdx.y;
  int tid = threadIdx.x;
  int w = tid >> 6, lane = tid & 63;
  int kg = lane >> 4, l16 = lane & 15;
  __shared__ float S_lds[2][16 * 64];
  __shared__ unsigned short P_lds[16 * 64];
  __shared__ float qr_sh[128];
  __shared__ float rope_lds[64];

  if (tid < 64) {
    float invf = exp2f(-L2INV * (float)tid);
    float x1 = qr_pre[b * HD_ + tid], x2 = qr_pre[b * HD_ + 64 + tid];
    float sn, cs; sincosf(4095.0f * invf, &sn, &cs);
    qr_sh[tid]      = x1 * cs - x2 * sn;
    qr_sh[64 + tid] = x1 * sn + x2 * cs;
  }
  __syncthreads();

  if constexpr (MODE != 3) { // ---- phase A (skipped only in MODE 3) ----
    int kh = w >> 2;
    int s_loc = (w & 3) * 16 + l16;
    int s = chunk * CHK + s_loc;
    const float* crow = (s == S_ - 1) ? (ckv_new + b * LOW_)
                                      : (ckv_cache + ((size_t)b * SPREV + s) * LOW_);
    f4v acc0 = {0.f, 0.f, 0.f, 0.f};
    f4v acc1 = {0.f, 0.f, 0.f, 0.f};
    const s8v* qf = (const s8v*)(qeff + (size_t)(b * H_ + l16) * LOW_);
    #pragma unroll
    for (int bt = 0; bt < 2; ++bt) {
      f4v c0_[4], c1_[4];
      s8v aq[4];
      #pragma unroll
      for (int u = 0; u < 4; ++u) {
        int kk = kh * 8 + bt * 4 + u;
        const float* cp = crow + kk * 32 + kg * 8;
        c0_[u] = *(const f4v*)cp;
        c1_[u] = *(const f4v*)(cp + 4);
        aq[u] = qf[kk * 4 + kg];
      }
      if constexpr (MODE == 1) {
        #pragma unroll
        for (int u = 0; u < 4; ++u) { sink_f4(c0_[u]); sink_f4(c1_[u]); sink_s8(aq[u]); }
      } else {
        #pragma unroll
        for (int u = 0; u < 4; ++u) {
          s8v bv;
          bv[0]=f2bf_s(c0_[u][0]); bv[1]=f2bf_s(c0_[u][1]);
          bv[2]=f2bf_s(c0_[u][2]); bv[3]=f2bf_s(c0_[u][3]);
          bv[4]=f2bf_s(c1_[u][0]); bv[5]=f2bf_s(c1_[u][1]);
          bv[6]=f2bf_s(c1_[u][2]); bv[7]=f2bf_s(c1_[u][3]);
          if (u & 1)
            acc1 = __builtin_amdgcn_mfma_f32_16x16x32_bf16(aq[u], bv, acc1, 0, 0, 0);
          else
            acc0 = __builtin_amdgcn_mfma_f32_16x16x32_bf16(aq[u], bv, acc0, 0, 0, 0);
        }
      }
    }
    if constexpr (MODE != 1) {
      #pragma unroll
      for (int r = 0; r < 4; ++r) {
        int h = kg * 4 + r;
        S_lds[kh][h * 64 + (s_loc ^ ((h & 7) << 2))] = acc0[r] + acc1[r];
      }
    }
    if (w < 4) { // rope loads (+math unless MODE 1)
      const float* krp = (s == S_ - 1) ? (kr_new + b * HD_)
                                       : (kr_cache + ((size_t)b * SPREV + s) * HD_);
      if constexpr (MODE == 1) {
        #pragma unroll
        for (int q = 0; q < 2; ++q) {
          f4v x1 = *(const f4v*)&krp[q * 64 + kg * 8];
          f4v x2 = *(const f4v*)&krp[q * 64 + kg * 8 + 4];
          sink_f4(x1); sink_f4(x2);
        }
      } else {
        float fs = (float)s;
        float rdot = 0.f;
        #pragma unroll
        for (int q = 0; q < 4; ++q) {
          int j = kg * 16 + q * 4;
          f4v x1 = *(const f4v*)&krp[j];
          f4v x2 = *(const f4v*)&krp[64 + j];
          f4v qa = *(const f4v*)&qr_sh[j];
          f4v qb = *(const f4v*)&qr_sh[64 + j];
          #pragma unroll
          for (int k2 = 0; k2 < 4; ++k2) {
            float invf = exp2f(-L2INV * (float)(j + k2));
            float sn, cs; sincosf(fs * invf, &sn, &cs);
            rdot += qa[k2] * (x1[k2] * cs - x2[k2] * sn)
                  + qb[k2] * (x1[k2] * sn + x2[k2] * cs);
          }
        }
        rdot += __shfl_xor(rdot, 16);
        rdot += __shfl_xor(rdot, 32);
        if (kg == 0) rope_lds[s_loc] = rdot;
      }
    }
  }
  __syncthreads();

  if constexpr (MODE != 1 && MODE != 3) { // ---- phase B ----
    int half = lane >> 5;
    int h = w * 2 + half;
    int sl = lane & 31;
    int s0 = sl * 2;
    int c2 = (h & 7) << 2;
    float v0 = (S_lds[0][h * 64 + (s0 ^ c2)] + S_lds[1][h * 64 + (s0 ^ c2)]
                + rope_lds[s0]) * 0.0625f;
    float v1 = (S_lds[0][h * 64 + ((s0 + 1) ^ c2)] + S_lds[1][h * 64 + ((s0 + 1) ^ c2)]
                + rope_lds[s0 + 1]) * 0.0625f;
    float m = fmaxf(v0, v1);
    m = fmaxf(m, __shfl_xor(m, 1));  m = fmaxf(m, __shfl_xor(m, 2));
    m = fmaxf(m, __shfl_xor(m, 4));  m = fmaxf(m, __shfl_xor(m, 8));
    m = fmaxf(m, __shfl_xor(m, 16));
    float e0 = expf(v0 - m), e1 = expf(v1 - m);
    float lsum = e0 + e1;
    lsum += __shfl_xor(lsum, 1);  lsum += __shfl_xor(lsum, 2);
    lsum += __shfl_xor(lsum, 4);  lsum += __shfl_xor(lsum, 8);
    lsum += __shfl_xor(lsum, 16);
    unsigned pk = (unsigned)(unsigned short)f2bf_s(e0) |
                  ((unsigned)(unsigned short)f2bf_s(e1) << 16);
    *(unsigned*)&P_lds[h * 64 + (s0 ^ ((h & 7) << 3))] = pk;
    if (sl == 0) {
      int idx = (b * NCH + chunk) * H_ + h;
      m_part[idx] = m;
      l_part[idx] = lsum;
    }
  }
  __syncthreads();

  if constexpr (MODE != 1 && MODE != 2) { // ---- phase C ----
    s8v pa[2];
    if constexpr (MODE == 3) {
      #pragma unroll
      for (int kt = 0; kt < 2; ++kt)
        #pragma unroll
        for (int i = 0; i < 8; ++i) pa[kt][i] = (short)0x3D80;  // bf16 0.0625
    } else {
      #pragma unroll
      for (int kt = 0; kt < 2; ++kt) {
        int so = kt * 32 + kg * 8;
        pa[kt] = *(const s8v*)&P_lds[l16 * 64 + (so ^ ((l16 & 7) << 3))];
      }
    }
    const float* rp[2][8];
    #pragma unroll
    for (int kt = 0; kt < 2; ++kt) {
      int so = kt * 32 + kg * 8;
      #pragma unroll
      for (int i = 0; i < 8; ++i) {
        int s = chunk * CHK + so + i;
        rp[kt][i] = (s == S_ - 1) ? (ckv_new + b * LOW_)
                                  : (ckv_cache + ((size_t)b * SPREV + s) * LOW_);
      }
    }
    f4v oa[4];
    #pragma unroll
    for (int nt = 0; nt < 4; ++nt) oa[nt] = {0.f, 0.f, 0.f, 0.f};
    #pragma unroll
    for (int nt = 0; nt < 4; ++nt) {
      int l = w * 64 + nt * 16 + l16;
      float vb0[8], vb1[8];
      #pragma unroll
      for (int i = 0; i < 8; ++i) { vb0[i] = rp[0][i][l]; vb1[i] = rp[1][i][l]; }
      s8v bv0, bv1;
      #pragma unroll
      for (int i = 0; i < 8; ++i) {
        bv0[i] = f2bf_s(vb0[i]);
        bv1[i] = f2bf_s(vb1[i]);
      }
      oa[nt] = __builtin_amdgcn_mfma_f32_16x16x32_bf16(pa[0], bv0, oa[nt], 0, 0, 0);
      oa[nt] = __builtin_amdgcn_mfma_f32_16x16x32_bf16(pa[1], bv1, oa[nt], 0, 0, 0);
    }
    if constexpr (MODE == 4) {
      #pragma unroll
      for (int nt = 0; nt < 4; ++nt) sink_f4(oa[nt]);
    } else {
      size_t base = (size_t)(b * NCH + chunk) * H_;
      #pragma unroll
      for (int nt = 0; nt < 4; ++nt) {
        int l = w * 64 + nt * 16 + l16;
        #pragma unroll
        for (int r = 0; r < 4; ++r) {
          int h = kg * 4 + r;
          acc_part[(base + h) * LOW_ + l] = (unsigned short)f2bf_s(oa[nt][r]);
        }
      }
    }
  }
}

// Fused combine + project. grid (16,8,8) x 128 thr.
__global__ __launch_bounds__(128) void reduce_proj_kernel(
    const float* __restrict__ m_part, const float* __restrict__ l_part,
    const unsigned short* __restrict__ acc_part, const float* __restrict__ FU,
    float* __restrict__ o_heads)
{
  int h = blockIdx.x, b = blockIdx.y, lz = blockIdx.z, t = threadIdx.x;
  __shared__ float wls[NCH];
  __shared__ float Linv_s;
  __shared__ float pa0[128], pa1[128];
  __shared__ float wl_sh[64];
  if (t < 64) {
    float mc = m_part[(b * NCH + t) * H_ + h];
    float M = mc;
    #pragma unroll
    for (int d = 1; d < 64; d <<= 1) M = fmaxf(M, __shfl_xor(M, d));
    float wc = expf(mc - M);
    float L = l_part[(b * NCH + t) * H_ + h] * wc;
    #pragma unroll
    for (int d = 1; d < 64; d <<= 1) L += __shfl_xor(L, d);
    wls[t] = wc;
    if (t == 0) Linv_s = 1.0f / L;
  }
  __syncthreads();
  {
    int p = t & 31, ch = t >> 5;
    int l0 = lz * 64 + p * 2;
    float a0 = 0.f, a1 = 0.f;
    const unsigned short* ap =
        acc_part + ((size_t)(b * NCH + ch * 16) * H_ + h) * LOW_ + l0;
    #pragma unroll 4
    for (int c = 0; c < 16; ++c) {
      unsigned pk = *(const unsigned*)(ap + (size_t)c * H_ * LOW_);
      float wc = wls[ch * 16 + c];
      a0 = fmaf(bf2f((unsigned short)(pk & 0xffffu)), wc, a0);
      a1 = fmaf(bf2f((unsigned short)(pk >> 16)),     wc, a1);
    }
    pa0[t] = a0; pa1[t] = a1;
  }
  __syncthreads();
  if (t < 32) {
    float inv = Linv_s;
    float s0 = pa0[t] + pa0[t + 32] + pa0[t + 64] + pa0[t + 96];
    float s1 = pa1[t] + pa1[t + 32] + pa1[t + 64] + pa1[t + 96];
    wl_sh[t * 2]     = s0 * inv;
    wl_sh[t * 2 + 1] = s1 * inv;
  }
  __syncthreads();
  {
    float a = 0.f;
    const float* fp = FU + (size_t)(lz * 64) * (2 * E_) + E_ + h * HD_ + t;
    #pragma unroll 4
    for (int l = 0; l < 64; ++l)
      a = fmaf(wl_sh[l], fp[(size_t)l * (2 * E_)], a);
    atomicAdd(&o_heads[(b * H_ + h) * HD_ + t], a);
  }
}

extern "C" void kernel_launch(void* const* d_in, const int* in_sizes, int n_in,
                              void* d_out, int out_size, void* d_ws, size_t ws_size,
                              hipStream_t stream)
{
  const float* x    = (const float*)d_in[0];
  const float* ckvc = (const float*)d_in[1];
  const float* krc  = (const float*)d_in[2];
  const float* Wdq  = (const float*)d_in[3];
  const float* Wuq  = (const float*)d_in[4];
  const float* Wqr  = (const float*)d_in[5];
  const float* Wdkv = (const float*)d_in[6];
  const float* Wkr  = (const float*)d_in[7];
  const float* FU   = (const float*)d_in[8];
  const float* Wo   = (const float*)d_in[9];
  float* out = (float*)d_out;

  char* ws = (char*)d_ws;
  // zeroed prefix (55296 floats):
  float* Cq             = (float*)(ws + 0);        // 65536 B
  float* Qc             = (float*)(ws + 65536);    // 65536 B
  float* qr_pre         = (float*)(ws + 131072);   // 4096 B
  float* ckvn           = (float*)(ws + 135168);   // 16384 B
  float* krn            = (float*)(ws + 151552);   // 4096 B
  float* o_heads        = (float*)(ws + 155648);   // 65536 B  [prefix end 221184]
  unsigned short* qeff  = (unsigned short*)(ws + 221184);  // 131072 B
  float* m_part         = (float*)(ws + 352256);   // 32768 B
  float* l_part         = (float*)(ws + 385024);   // 32768 B
  unsigned short* accp  = (unsigned short*)(ws + 417792);  // 8388608 B
  // ablation dummies:
  unsigned short* accp_d = (unsigned short*)(ws + 8806400);  // 8388608 B
  float* m_d            = (float*)(ws + 17195008); // 32768 B
  float* l_d            = (float*)(ws + 17227776); // 32768 B (~17.3 MB)

  init_kernel<<<280, 256, 0, stream>>>((float*)ws, out);
  matvec8<<<dim3(21, 64), 128, 0, stream>>>(x, E_, Wdq, E_, Cq,
                                            Wdkv, LOW_, ckvn, Wkr, HD_, krn);
  matvec8<<<dim3(17, 64), 128, 0, stream>>>(Cq, E_, Wuq, E_, Qc,
                                            Wqr, HD_, qr_pre,
                                            (const float*)nullptr, 0, (float*)nullptr);
  qeff_kernel<<<dim3(64, 8), 256, 0, stream>>>(Qc, FU, qeff);

  // ---- ablation dispatches (dummy outputs), then the real attn ----
  attn_kernel<1><<<dim3(64, 8), 512, 0, stream>>>(ckvc, ckvn, qeff, krc, krn,
                                                  qr_pre, accp_d, m_d, l_d);
  attn_kernel<2><<<dim3(64, 8), 512, 0, stream>>>(ckvc, ckvn, qeff, krc, krn,
                                                  qr_pre, accp_d, m_d, l_d);
  attn_kernel<3><<<dim3(64, 8), 512, 0, stream>>>(ckvc, ckvn, qeff, krc, krn,
                                                  qr_pre, accp_d, m_d, l_d);
  attn_kernel<4><<<dim3(64, 8), 512, 0, stream>>>(ckvc, ckvn, qeff, krc, krn,
                                                  qr_pre, accp_d, m_d, l_d);
  attn_kernel<0><<<dim3(64, 8), 512, 0, stream>>>(ckvc, ckvn, qeff, krc, krn,
                                                  qr_pre, accp, m_part, l_part);

  reduce_proj_kernel<<<dim3(16, 8, 8), 128, 0, stream>>>(m_part, l_part, accp,
                                                         FU, o_heads);
  matvec8<<<dim3(16, 64), 128, 0, stream>>>(o_heads, E_, Wo, E_, out,
                                            (const float*)nullptr, 0, (float*)nullptr,
                                            (const float*)nullptr, 0, (float*)nullptr);
}

// Round 21
// 92.569 us; speedup vs baseline: 1.6587x; 1.6587x over previous
//
#include <hip/hip_runtime.h>
#include <hip/hip_bf16.h>

#define B_ 8
#define SPREV 4095
#define S_ 4096
#define E_ 2048
#define H_ 16
#define HD_ 128
#define LOW_ 512
#define NCH 128     // attention s-chunks per batch
#define CHK 32      // positions per chunk
#define L2INV 0.207620506f   // log2(10000)/64

typedef short s8v __attribute__((ext_vector_type(8)));
typedef float f4v __attribute__((ext_vector_type(4)));

#define GAS(p) ((const __attribute__((address_space(1))) void*)(p))
#define LAS(p) ((__attribute__((address_space(3))) void*)(p))

__device__ __forceinline__ short f2bf_s(float f) {
  return (short)__bfloat16_as_ushort(__float2bfloat16(f));
}
__device__ __forceinline__ float bf2f(unsigned short h) {
  union { unsigned u; float f; } v; v.u = ((unsigned)h) << 16;
  return v.f;
}

// Zero all accumulation targets (55296 ws floats + 16384 out floats).
__global__ __launch_bounds__(256) void init_kernel(float* __restrict__ ws_pre,
                                                   float* __restrict__ out) {
  int i = blockIdx.x * 256 + threadIdx.x;
  if (i < 55296) ws_pre[i] = 0.f;           // Cq,Qc,qr_pre,ckvn,krn,o_heads
  else if (i < 71680) out[i - 55296] = 0.f;
}

// out[b][n] += sum_k x[b][k] * W[k][n], k in [k0, k0+32).
__global__ __launch_bounds__(128) void matvec8(
    const float* __restrict__ x, int K,
    const float* __restrict__ W0, int N0, float* __restrict__ o0,
    const float* __restrict__ W1, int N1, float* __restrict__ o1,
    const float* __restrict__ W2, int N2, float* __restrict__ o2)
{
  int cb = blockIdx.x;
  int nb0 = N0 >> 7, nb1 = N1 >> 7;
  const float* W; float* o; int N, colbase;
  if (cb < nb0)            { W = W0; o = o0; N = N0; colbase = cb << 7; }
  else if (cb < nb0 + nb1) { W = W1; o = o1; N = N1; colbase = (cb - nb0) << 7; }
  else                     { W = W2; o = o2; N = N2; colbase = (cb - nb0 - nb1) << 7; }
  int col = colbase + threadIdx.x;
  int k0 = blockIdx.y * 32;
  float acc[B_];
  #pragma unroll
  for (int b = 0; b < B_; ++b) acc[b] = 0.f;
  const float* Wp = W + (size_t)k0 * N + col;
  #pragma unroll 8
  for (int k = 0; k < 32; ++k) {
    float wv = Wp[(size_t)k * N];
    #pragma unroll
    for (int b = 0; b < B_; ++b)
      acc[b] = fmaf(x[b * K + k0 + k], wv, acc[b]);   // uniform -> s_load
  }
  #pragma unroll
  for (int b = 0; b < B_; ++b) atomicAdd(&o[b * N + col], acc[b]);
}

// qeff[b,h,l] = sum_d FU[l, h*128+d] * Qc[b, h*128+d]; grid (64, 8) x 256.
__global__ __launch_bounds__(256) void qeff_kernel(
    const float* __restrict__ Qc, const float* __restrict__ FU,
    unsigned short* __restrict__ qeff)
{
  int bx = blockIdx.x, b = blockIdx.y, t = threadIdx.x;
  int h = bx >> 2, lq = bx & 3;
  int g = t >> 4, li = t & 15;
  __shared__ float qs[HD_];
  if (t < 128) qs[t] = Qc[b * E_ + h * HD_ + t];
  __syncthreads();
  f4v q0 = *(const f4v*)&qs[li * 8];
  f4v q1 = *(const f4v*)&qs[li * 8 + 4];
  #pragma unroll 2
  for (int p = 0; p < 8; ++p) {
    int l = lq * 128 + p * 16 + g;
    const f4v* w4 = (const f4v*)(FU + (size_t)l * (2 * E_) + h * HD_ + li * 8);
    f4v w0 = w4[0], w1 = w4[1];
    float a = w0[0]*q0[0] + w0[1]*q0[1] + w0[2]*q0[2] + w0[3]*q0[3]
            + w1[0]*q1[0] + w1[1]*q1[1] + w1[2]*q1[2] + w1[3]*q1[3];
    a += __shfl_xor(a, 1); a += __shfl_xor(a, 2);
    a += __shfl_xor(a, 4); a += __shfl_xor(a, 8);
    if (li == 0) qeff[(size_t)(b * H_ + h) * LOW_ + l] = (unsigned short)f2bf_s(a);
  }
}

// Flash-decode, one (b, 32-chunk) per block, 8 waves (512 thr).
// STAGE: 32x512 f32 ckv tile -> LDS via global_load_lds width-16, coalesced
// 1KB/instr; source pre-swizzled by granule gc(r)=(r&7)^(((r>>3)&3)<<1),
// which gives <=2-way bank aliasing in BOTH phase-A b128 reads and phase-C
// scalar column reads (verified: per-instr (row,granule) pairs cover all 8
// bank-groups exactly twice).
__global__ __launch_bounds__(512) void attn_kernel(
    const float* __restrict__ ckv_cache, const float* __restrict__ ckv_new,
    const unsigned short* __restrict__ qeff,
    const float* __restrict__ kr_cache, const float* __restrict__ kr_new,
    const float* __restrict__ qr_pre,
    unsigned short* __restrict__ acc_part, float* __restrict__ m_part,
    float* __restrict__ l_part)
{
  int chunk = blockIdx.x, b = blockIdx.y;
  int tid = threadIdx.x;
  int w = tid >> 6, lane = tid & 63;
  int kg = lane >> 4, l16 = lane & 15;
  __shared__ float V32[CHK * 512];          // 64 KB, granule-swizzled f32
  __shared__ float S_lds[4][16 * 32];       // [k-quarter][h*32 + (s ^ ((h&7)<<2))]
  __shared__ unsigned short P_lds[16 * 32]; // granule-swz: s ^ ((h&3)<<3)
  __shared__ float qr_sh[128];
  __shared__ float rope_lds[CHK];

  // qr rotated at position 4095 (once per block)
  if (tid < 64) {
    float invf = exp2f(-L2INV * (float)tid);
    float x1 = qr_pre[b * HD_ + tid], x2 = qr_pre[b * HD_ + 64 + tid];
    float sn, cs; sincosf(4095.0f * invf, &sn, &cs);
    qr_sh[tid]      = x1 * cs - x2 * sn;
    qr_sh[64 + tid] = x1 * sn + x2 * cs;
  }

  { // ---- STAGE: 64 segs x 1KB; wave w issues segs w*8..w*8+7 ----
    char* vbase = (char*)V32;
    #pragma unroll
    for (int i = 0; i < 8; ++i) {
      int seg = w * 8 + i;
      int r = seg >> 1, half = seg & 1;
      int sg = chunk * CHK + r;
      const float* crow = (sg == S_ - 1) ? (ckv_new + b * LOW_)
                                         : (ckv_cache + ((size_t)b * SPREV + sg) * LOW_);
      int c = (r & 7) ^ (((r >> 3) & 3) << 1);
      const float* gp = crow + (((half * 64 + lane) ^ c) << 2);
      __builtin_amdgcn_global_load_lds(GAS(gp), LAS(vbase + seg * 1024), 16, 0, 0);
    }
  }
  __syncthreads();   // compiler drains vmcnt before barrier

  { // ---- phase A: wave w = (s-group w&1, k-quarter w>>1), frags from LDS ----
    int kq = w >> 1;
    int s_loc = (w & 1) * 16 + l16;
    int c = (s_loc & 7) ^ (((s_loc >> 3) & 3) << 1);
    const float* vrow = V32 + s_loc * 512;
    f4v acc0 = {0.f, 0.f, 0.f, 0.f};
    f4v acc1 = {0.f, 0.f, 0.f, 0.f};
    const s8v* qf = (const s8v*)(qeff + (size_t)(b * H_ + l16) * LOW_);
    #pragma unroll
    for (int u = 0; u < 4; ++u) {
      int kk = kq * 4 + u;
      s8v a = qf[kk * 4 + kg];
      int g = kk * 8 + kg * 2;
      f4v c0 = *(const f4v*)(vrow + ((g ^ c) << 2));
      f4v c1 = *(const f4v*)(vrow + (((g + 1) ^ c) << 2));
      s8v bv;
      bv[0]=f2bf_s(c0[0]); bv[1]=f2bf_s(c0[1]); bv[2]=f2bf_s(c0[2]); bv[3]=f2bf_s(c0[3]);
      bv[4]=f2bf_s(c1[0]); bv[5]=f2bf_s(c1[1]); bv[6]=f2bf_s(c1[2]); bv[7]=f2bf_s(c1[3]);
      if (u & 1)
        acc1 = __builtin_amdgcn_mfma_f32_16x16x32_bf16(a, bv, acc1, 0, 0, 0);
      else
        acc0 = __builtin_amdgcn_mfma_f32_16x16x32_bf16(a, bv, acc0, 0, 0, 0);
    }
    #pragma unroll
    for (int r = 0; r < 4; ++r) {
      int h = kg * 4 + r;
      S_lds[kq][h * 32 + (s_loc ^ ((h & 7) << 2))] = acc0[r] + acc1[r];
    }
    if (kq == 0) { // rope for this s: j in [kg*16, kg*16+16), shfl reduce
      int s = chunk * CHK + s_loc;
      const float* krp = (s == S_ - 1) ? (kr_new + b * HD_)
                                       : (kr_cache + ((size_t)b * SPREV + s) * HD_);
      float fs = (float)s;
      float rdot = 0.f;
      #pragma unroll
      for (int q = 0; q < 4; ++q) {
        int j = kg * 16 + q * 4;
        f4v x1 = *(const f4v*)&krp[j];
        f4v x2 = *(const f4v*)&krp[64 + j];
        f4v qa = *(const f4v*)&qr_sh[j];
        f4v qb = *(const f4v*)&qr_sh[64 + j];
        #pragma unroll
        for (int k2 = 0; k2 < 4; ++k2) {
          float invf = exp2f(-L2INV * (float)(j + k2));
          float sn, cs; sincosf(fs * invf, &sn, &cs);
          rdot += qa[k2] * (x1[k2] * cs - x2[k2] * sn)
                + qb[k2] * (x1[k2] * sn + x2[k2] * cs);
        }
      }
      rdot += __shfl_xor(rdot, 16);
      rdot += __shfl_xor(rdot, 32);
      if (kg == 0) rope_lds[s_loc] = rdot;
    }
  }
  __syncthreads();

  { // ---- phase B: 512 thr; thread = (h = tid>>5, sl = tid&31) ----
    int h = tid >> 5, sl = tid & 31;
    int c2 = (h & 7) << 2;
    float v = (S_lds[0][h * 32 + (sl ^ c2)] + S_lds[1][h * 32 + (sl ^ c2)]
             + S_lds[2][h * 32 + (sl ^ c2)] + S_lds[3][h * 32 + (sl ^ c2)]
             + rope_lds[sl]) * 0.0625f;
    float m = v;
    m = fmaxf(m, __shfl_xor(m, 1));  m = fmaxf(m, __shfl_xor(m, 2));
    m = fmaxf(m, __shfl_xor(m, 4));  m = fmaxf(m, __shfl_xor(m, 8));
    m = fmaxf(m, __shfl_xor(m, 16));
    float e = expf(v - m);
    float lsum = e;
    lsum += __shfl_xor(lsum, 1);  lsum += __shfl_xor(lsum, 2);
    lsum += __shfl_xor(lsum, 4);  lsum += __shfl_xor(lsum, 8);
    lsum += __shfl_xor(lsum, 16);
    P_lds[h * 32 + (sl ^ ((h & 3) << 3))] = (unsigned short)f2bf_s(e);
    if (sl == 0) {
      int idx = (b * NCH + chunk) * H_ + h;
      m_part[idx] = m;
      l_part[idx] = lsum;
    }
  }
  __syncthreads();

  { // ---- phase C: wave w owns l in [w*64, w*64+64); V cols from LDS ----
    s8v pa = *(const s8v*)&P_lds[l16 * 32 + ((kg * 8) ^ ((l16 & 3) << 3))];
    f4v oa[4];
    #pragma unroll
    for (int nt = 0; nt < 4; ++nt) oa[nt] = {0.f, 0.f, 0.f, 0.f};
    #pragma unroll
    for (int nt = 0; nt < 4; ++nt) {
      int l = w * 64 + nt * 16 + l16;
      int g = l >> 2, e = l & 3;
      s8v bv;
      #pragma unroll
      for (int i = 0; i < 8; ++i) {
        int r = kg * 8 + i;
        int c = (r & 7) ^ (((r >> 3) & 3) << 1);
        bv[i] = f2bf_s(V32[r * 512 + ((g ^ c) << 2) + e]);
      }
      oa[nt] = __builtin_amdgcn_mfma_f32_16x16x32_bf16(pa, bv, oa[nt], 0, 0, 0);
    }
    size_t base = (size_t)(b * NCH + chunk) * H_;
    #pragma unroll
    for (int nt = 0; nt < 4; ++nt) {
      int l = w * 64 + nt * 16 + l16;
      #pragma unroll
      for (int r = 0; r < 4; ++r) {
        int h = kg * 4 + r;
        acc_part[(base + h) * LOW_ + l] = (unsigned short)f2bf_s(oa[nt][r]);
      }
    }
  }
}

// Fused combine + project; 128 chunks (cross-wave reduce). grid (16,8,8) x 128.
__global__ __launch_bounds__(128) void reduce_proj_kernel(
    const float* __restrict__ m_part, const float* __restrict__ l_part,
    const unsigned short* __restrict__ acc_part, const float* __restrict__ FU,
    float* __restrict__ o_heads)
{
  int h = blockIdx.x, b = blockIdx.y, lz = blockIdx.z, t = threadIdx.x;
  int w = t >> 6, lane = t & 63;
  __shared__ float wls[NCH];
  __shared__ float red[4];
  __shared__ float pa0[128], pa1[128];
  __shared__ float wl_sh[64];
  float mc = m_part[(b * NCH + t) * H_ + h];
  float M = mc;
  #pragma unroll
  for (int d = 1; d < 64; d <<= 1) M = fmaxf(M, __shfl_xor(M, d));
  if (lane == 0) red[w] = M;
  __syncthreads();
  M = fmaxf(red[0], red[1]);
  float wc = expf(mc - M);
  wls[t] = wc;
  float L = l_part[(b * NCH + t) * H_ + h] * wc;
  #pragma unroll
  for (int d = 1; d < 64; d <<= 1) L += __shfl_xor(L, d);
  if (lane == 0) red[2 + w] = L;
  __syncthreads();
  float Linv = 1.0f / (red[2] + red[3]);
  {
    int p = t & 31, ch = t >> 5;
    int l0 = lz * 64 + p * 2;
    float a0 = 0.f, a1 = 0.f;
    const unsigned short* ap =
        acc_part + ((size_t)(b * NCH + ch * 32) * H_ + h) * LOW_ + l0;
    #pragma unroll 4
    for (int c = 0; c < 32; ++c) {
      unsigned pk = *(const unsigned*)(ap + (size_t)c * H_ * LOW_);
      float wc2 = wls[ch * 32 + c];
      a0 = fmaf(bf2f((unsigned short)(pk & 0xffffu)), wc2, a0);
      a1 = fmaf(bf2f((unsigned short)(pk >> 16)),     wc2, a1);
    }
    pa0[t] = a0; pa1[t] = a1;
  }
  __syncthreads();
  if (t < 32) {
    float s0 = pa0[t] + pa0[t + 32] + pa0[t + 64] + pa0[t + 96];
    float s1 = pa1[t] + pa1[t + 32] + pa1[t + 64] + pa1[t + 96];
    wl_sh[t * 2]     = s0 * Linv;
    wl_sh[t * 2 + 1] = s1 * Linv;
  }
  __syncthreads();
  {
    float a = 0.f;
    const float* fp = FU + (size_t)(lz * 64) * (2 * E_) + E_ + h * HD_ + t;
    #pragma unroll 4
    for (int l = 0; l < 64; ++l)
      a = fmaf(wl_sh[l], fp[(size_t)l * (2 * E_)], a);
    atomicAdd(&o_heads[(b * H_ + h) * HD_ + t], a);
  }
}

extern "C" void kernel_launch(void* const* d_in, const int* in_sizes, int n_in,
                              void* d_out, int out_size, void* d_ws, size_t ws_size,
                              hipStream_t stream)
{
  const float* x    = (const float*)d_in[0];
  const float* ckvc = (const float*)d_in[1];
  const float* krc  = (const float*)d_in[2];
  const float* Wdq  = (const float*)d_in[3];
  const float* Wuq  = (const float*)d_in[4];
  const float* Wqr  = (const float*)d_in[5];
  const float* Wdkv = (const float*)d_in[6];
  const float* Wkr  = (const float*)d_in[7];
  const float* FU   = (const float*)d_in[8];
  const float* Wo   = (const float*)d_in[9];
  float* out = (float*)d_out;

  char* ws = (char*)d_ws;
  // zeroed prefix (55296 floats):
  float* Cq             = (float*)(ws + 0);        // 65536 B
  float* Qc             = (float*)(ws + 65536);    // 65536 B
  float* qr_pre         = (float*)(ws + 131072);   // 4096 B
  float* ckvn           = (float*)(ws + 135168);   // 16384 B
  float* krn            = (float*)(ws + 151552);   // 4096 B
  float* o_heads        = (float*)(ws + 155648);   // 65536 B  [prefix end 221184]
  unsigned short* qeff  = (unsigned short*)(ws + 221184);  // 131072 B
  float* m_part         = (float*)(ws + 352256);   // 65536 B
  float* l_part         = (float*)(ws + 417792);   // 65536 B
  unsigned short* accp  = (unsigned short*)(ws + 483328);  // 16777216 B (~17.3 MB)

  // Zero all atomic targets
  init_kernel<<<280, 256, 0, stream>>>((float*)ws, out);

  // Cq = x@Wdq ; ckv_new = x@Wdkv ; kr_new = x@Wkr
  matvec8<<<dim3(21, 64), 128, 0, stream>>>(x, E_, Wdq, E_, Cq,
                                            Wdkv, LOW_, ckvn, Wkr, HD_, krn);
  // Qc = Cq@Wuq ; qr_pre = Cq@Wqr
  matvec8<<<dim3(17, 64), 128, 0, stream>>>(Cq, E_, Wuq, E_, Qc,
                                            Wqr, HD_, qr_pre,
                                            (const float*)nullptr, 0, (float*)nullptr);
  qeff_kernel<<<dim3(64, 8), 256, 0, stream>>>(Qc, FU, qeff);
  attn_kernel<<<dim3(128, 8), 512, 0, stream>>>(ckvc, ckvn, qeff, krc, krn,
                                                qr_pre, accp, m_part, l_part);
  reduce_proj_kernel<<<dim3(16, 8, 8), 128, 0, stream>>>(m_part, l_part, accp,
                                                         FU, o_heads);
  // out = o_heads @ Wo
  matvec8<<<dim3(16, 64), 128, 0, stream>>>(o_heads, E_, Wo, E_, out,
                                            (const float*)nullptr, 0, (float*)nullptr,
                                            (const float*)nullptr, 0, (float*)nullptr);
}

// Round 22
// 85.972 us; speedup vs baseline: 1.7860x; 1.0767x over previous
//
#include <hip/hip_runtime.h>
#include <hip/hip_bf16.h>

#define B_ 8
#define SPREV 4095
#define S_ 4096
#define E_ 2048
#define H_ 16
#define HD_ 128
#define LOW_ 512
#define NCH 64      // attention s-chunks per batch
#define CHK 64      // positions per chunk
#define L2INV 0.207620506f   // log2(10000)/64
#define CKV4_N 4193280       // total ckv_cache float4 count (8*4095*512/4)
#define CKV4_H 2096640       // half

typedef short s8v __attribute__((ext_vector_type(8)));
typedef float f4v __attribute__((ext_vector_type(4)));

__device__ __forceinline__ short f2bf_s(float f) {
  return (short)__bfloat16_as_ushort(__float2bfloat16(f));
}
__device__ __forceinline__ float bf2f(unsigned short h) {
  union { unsigned u; float f; } v; v.u = ((unsigned)h) << 16;
  return v.f;
}
// DCE sink (rule 17): keep prefetched registers live without cost.
__device__ __forceinline__ void sink_f4(f4v v) {
  asm volatile("" :: "v"(v[0]), "v"(v[1]), "v"(v[2]), "v"(v[3]));
}

// Zero all accumulation targets (55296 ws floats + 16384 out floats).
__global__ __launch_bounds__(256) void init_kernel(float* __restrict__ ws_pre,
                                                   float* __restrict__ out) {
  int i = blockIdx.x * 256 + threadIdx.x;
  if (i < 55296) ws_pre[i] = 0.f;           // Cq,Qc,qr_pre,ckvn,krn,o_heads
  else if (i < 71680) out[i - 55296] = 0.f;
}

// out[b][n] += sum_k x[b][k] * W[k][n], k in [k0, k0+32). Blocks past the
// real column-blocks stream-prefetch ckv (L3 warming for attn).
__global__ __launch_bounds__(128) void matvec8(
    const float* __restrict__ x, int K,
    const float* __restrict__ W0, int N0, float* __restrict__ o0,
    const float* __restrict__ W1, int N1, float* __restrict__ o1,
    const float* __restrict__ W2, int N2, float* __restrict__ o2,
    const float* __restrict__ pf4, int pf_base4, int pf_n4, int pf_nb)
{
  int cb = blockIdx.x;
  int nb0 = N0 >> 7, nb1 = N1 >> 7, nb2 = N2 >> 7;
  int nbsum = nb0 + nb1 + nb2;
  if (cb >= nbsum) { // ---- prefetch family ----
    int seg = (cb - nbsum) * gridDim.y + blockIdx.y;
    int ftid = seg * 128 + threadIdx.x;
    const f4v* p4 = (const f4v*)pf4;
    for (int i = pf_base4 + ftid; i < pf_base4 + pf_n4; i += pf_nb * 128) {
      f4v v = p4[i]; sink_f4(v);
    }
    return;
  }
  const float* W; float* o; int N, colbase;
  if (cb < nb0)            { W = W0; o = o0; N = N0; colbase = cb << 7; }
  else if (cb < nb0 + nb1) { W = W1; o = o1; N = N1; colbase = (cb - nb0) << 7; }
  else                     { W = W2; o = o2; N = N2; colbase = (cb - nb0 - nb1) << 7; }
  int col = colbase + threadIdx.x;
  int k0 = blockIdx.y * 32;
  float acc[B_];
  #pragma unroll
  for (int b = 0; b < B_; ++b) acc[b] = 0.f;
  const float* Wp = W + (size_t)k0 * N + col;
  #pragma unroll 8
  for (int k = 0; k < 32; ++k) {
    float wv = Wp[(size_t)k * N];
    #pragma unroll
    for (int b = 0; b < B_; ++b)
      acc[b] = fmaf(x[b * K + k0 + k], wv, acc[b]);   // uniform -> s_load
  }
  #pragma unroll
  for (int b = 0; b < B_; ++b) atomicAdd(&o[b * N + col], acc[b]);
}

// qeff[b,h,l] = sum_d FU[l, h*128+d] * Qc[b, h*128+d]; grid (128, 8) x 256.
// Blocks bx>=64 stream-prefetch the second half of ckv.
__global__ __launch_bounds__(256) void qeff_kernel(
    const float* __restrict__ Qc, const float* __restrict__ FU,
    unsigned short* __restrict__ qeff,
    const float* __restrict__ pf4, int pf_base4, int pf_n4)
{
  int bx = blockIdx.x, b = blockIdx.y, t = threadIdx.x;
  if (bx >= 64) { // ---- prefetch family: 64 x-slots x 8 y = 512 blocks ----
    int seg = (bx - 64) * 8 + b;
    int ftid = seg * 256 + t;
    const f4v* p4 = (const f4v*)pf4;
    for (int i = pf_base4 + ftid; i < pf_base4 + pf_n4; i += 512 * 256) {
      f4v v = p4[i]; sink_f4(v);
    }
    return;
  }
  int h = bx >> 2, lq = bx & 3;
  int g = t >> 4, li = t & 15;
  __shared__ float qs[HD_];
  if (t < 128) qs[t] = Qc[b * E_ + h * HD_ + t];
  __syncthreads();
  f4v q0 = *(const f4v*)&qs[li * 8];
  f4v q1 = *(const f4v*)&qs[li * 8 + 4];
  #pragma unroll 2
  for (int p = 0; p < 8; ++p) {
    int l = lq * 128 + p * 16 + g;
    const f4v* w4 = (const f4v*)(FU + (size_t)l * (2 * E_) + h * HD_ + li * 8);
    f4v w0 = w4[0], w1 = w4[1];
    float a = w0[0]*q0[0] + w0[1]*q0[1] + w0[2]*q0[2] + w0[3]*q0[3]
            + w1[0]*q1[0] + w1[1]*q1[1] + w1[2]*q1[2] + w1[3]*q1[3];
    a += __shfl_xor(a, 1); a += __shfl_xor(a, 2);
    a += __shfl_xor(a, 4); a += __shfl_xor(a, 8);
    if (li == 0) qeff[(size_t)(b * H_ + h) * LOW_ + l] = (unsigned short)f2bf_s(a);
  }
}

// Flash-decode, one (b, 64-chunk) per block, 8 waves (512 thr). (= round 17)
__global__ __launch_bounds__(512) void attn_kernel(
    const float* __restrict__ ckv_cache, const float* __restrict__ ckv_new,
    const unsigned short* __restrict__ qeff,
    const float* __restrict__ kr_cache, const float* __restrict__ kr_new,
    const float* __restrict__ qr_pre,
    unsigned short* __restrict__ acc_part, float* __restrict__ m_part,
    float* __restrict__ l_part)
{
  int chunk = blockIdx.x, b = blockIdx.y;
  int tid = threadIdx.x;
  int w = tid >> 6, lane = tid & 63;
  int kg = lane >> 4, l16 = lane & 15;
  __shared__ float S_lds[2][16 * 64];       // [k-half][h*64 + (s ^ ((h&7)<<2))]
  __shared__ unsigned short P_lds[16 * 64]; // swizzled: h*64 + (s ^ ((h&7)<<3))
  __shared__ float qr_sh[128];
  __shared__ float rope_lds[64];

  if (tid < 64) {
    float invf = exp2f(-L2INV * (float)tid);
    float x1 = qr_pre[b * HD_ + tid], x2 = qr_pre[b * HD_ + 64 + tid];
    float sn, cs; sincosf(4095.0f * invf, &sn, &cs);
    qr_sh[tid]      = x1 * cs - x2 * sn;
    qr_sh[64 + tid] = x1 * sn + x2 * cs;
  }
  __syncthreads();

  { // ---- phase A: all 8 waves; k-split + 4-kk register batch prefetch ----
    int kh = w >> 2;
    int s_loc = (w & 3) * 16 + l16;
    int s = chunk * CHK + s_loc;
    const float* crow = (s == S_ - 1) ? (ckv_new + b * LOW_)
                                      : (ckv_cache + ((size_t)b * SPREV + s) * LOW_);
    f4v acc0 = {0.f, 0.f, 0.f, 0.f};
    f4v acc1 = {0.f, 0.f, 0.f, 0.f};
    const s8v* qf = (const s8v*)(qeff + (size_t)(b * H_ + l16) * LOW_);
    #pragma unroll
    for (int bt = 0; bt < 2; ++bt) {
      f4v c0_[4], c1_[4];
      s8v aq[4];
      #pragma unroll
      for (int u = 0; u < 4; ++u) {
        int kk = kh * 8 + bt * 4 + u;
        const float* cp = crow + kk * 32 + kg * 8;
        c0_[u] = *(const f4v*)cp;
        c1_[u] = *(const f4v*)(cp + 4);
        aq[u] = qf[kk * 4 + kg];
      }
      #pragma unroll
      for (int u = 0; u < 4; ++u) {
        s8v bv;
        bv[0]=f2bf_s(c0_[u][0]); bv[1]=f2bf_s(c0_[u][1]);
        bv[2]=f2bf_s(c0_[u][2]); bv[3]=f2bf_s(c0_[u][3]);
        bv[4]=f2bf_s(c1_[u][0]); bv[5]=f2bf_s(c1_[u][1]);
        bv[6]=f2bf_s(c1_[u][2]); bv[7]=f2bf_s(c1_[u][3]);
        if (u & 1)
          acc1 = __builtin_amdgcn_mfma_f32_16x16x32_bf16(aq[u], bv, acc1, 0, 0, 0);
        else
          acc0 = __builtin_amdgcn_mfma_f32_16x16x32_bf16(aq[u], bv, acc0, 0, 0, 0);
      }
    }
    #pragma unroll
    for (int r = 0; r < 4; ++r) {
      int h = kg * 4 + r;
      S_lds[kh][h * 64 + (s_loc ^ ((h & 7) << 2))] = acc0[r] + acc1[r];
    }
    if (w < 4) {
      const float* krp = (s == S_ - 1) ? (kr_new + b * HD_)
                                       : (kr_cache + ((size_t)b * SPREV + s) * HD_);
      float fs = (float)s;
      float rdot = 0.f;
      #pragma unroll
      for (int q = 0; q < 4; ++q) {
        int j = kg * 16 + q * 4;
        f4v x1 = *(const f4v*)&krp[j];
        f4v x2 = *(const f4v*)&krp[64 + j];
        f4v qa = *(const f4v*)&qr_sh[j];
        f4v qb = *(const f4v*)&qr_sh[64 + j];
        #pragma unroll
        for (int k2 = 0; k2 < 4; ++k2) {
          float invf = exp2f(-L2INV * (float)(j + k2));
          float sn, cs; sincosf(fs * invf, &sn, &cs);
          rdot += qa[k2] * (x1[k2] * cs - x2[k2] * sn)
                + qb[k2] * (x1[k2] * sn + x2[k2] * cs);
        }
      }
      rdot += __shfl_xor(rdot, 16);
      rdot += __shfl_xor(rdot, 32);
      if (kg == 0) rope_lds[s_loc] = rdot;
    }
  }
  __syncthreads();

  { // ---- phase B: all 8 waves; wave w owns h = 2w + (lane>>5), 2 s/lane ----
    int half = lane >> 5;
    int h = w * 2 + half;
    int sl = lane & 31;
    int s0 = sl * 2;
    int c2 = (h & 7) << 2;
    float v0 = (S_lds[0][h * 64 + (s0 ^ c2)] + S_lds[1][h * 64 + (s0 ^ c2)]
                + rope_lds[s0]) * 0.0625f;
    float v1 = (S_lds[0][h * 64 + ((s0 + 1) ^ c2)] + S_lds[1][h * 64 + ((s0 + 1) ^ c2)]
                + rope_lds[s0 + 1]) * 0.0625f;
    float m = fmaxf(v0, v1);
    m = fmaxf(m, __shfl_xor(m, 1));  m = fmaxf(m, __shfl_xor(m, 2));
    m = fmaxf(m, __shfl_xor(m, 4));  m = fmaxf(m, __shfl_xor(m, 8));
    m = fmaxf(m, __shfl_xor(m, 16));
    float e0 = expf(v0 - m), e1 = expf(v1 - m);
    float lsum = e0 + e1;
    lsum += __shfl_xor(lsum, 1);  lsum += __shfl_xor(lsum, 2);
    lsum += __shfl_xor(lsum, 4);  lsum += __shfl_xor(lsum, 8);
    lsum += __shfl_xor(lsum, 16);
    unsigned pk = (unsigned)(unsigned short)f2bf_s(e0) |
                  ((unsigned)(unsigned short)f2bf_s(e1) << 16);
    *(unsigned*)&P_lds[h * 64 + (s0 ^ ((h & 7) << 3))] = pk;
    if (sl == 0) {
      int idx = (b * NCH + chunk) * H_ + h;
      m_part[idx] = m;
      l_part[idx] = lsum;
    }
  }
  __syncthreads();

  { // ---- phase C: wave w owns l in [w*64, w*64+64) ----
    s8v pa[2];
    const float* rp[2][8];
    #pragma unroll
    for (int kt = 0; kt < 2; ++kt) {
      int so = kt * 32 + kg * 8;
      pa[kt] = *(const s8v*)&P_lds[l16 * 64 + (so ^ ((l16 & 7) << 3))];
      #pragma unroll
      for (int i = 0; i < 8; ++i) {
        int s = chunk * CHK + so + i;
        rp[kt][i] = (s == S_ - 1) ? (ckv_new + b * LOW_)
                                  : (ckv_cache + ((size_t)b * SPREV + s) * LOW_);
      }
    }
    f4v oa[4];
    #pragma unroll
    for (int nt = 0; nt < 4; ++nt) oa[nt] = {0.f, 0.f, 0.f, 0.f};
    #pragma unroll
    for (int nt = 0; nt < 4; ++nt) {
      int l = w * 64 + nt * 16 + l16;
      float vb0[8], vb1[8];
      #pragma unroll
      for (int i = 0; i < 8; ++i) { vb0[i] = rp[0][i][l]; vb1[i] = rp[1][i][l]; }
      s8v bv0, bv1;
      #pragma unroll
      for (int i = 0; i < 8; ++i) {
        bv0[i] = f2bf_s(vb0[i]);
        bv1[i] = f2bf_s(vb1[i]);
      }
      oa[nt] = __builtin_amdgcn_mfma_f32_16x16x32_bf16(pa[0], bv0, oa[nt], 0, 0, 0);
      oa[nt] = __builtin_amdgcn_mfma_f32_16x16x32_bf16(pa[1], bv1, oa[nt], 0, 0, 0);
    }
    size_t base = (size_t)(b * NCH + chunk) * H_;
    #pragma unroll
    for (int nt = 0; nt < 4; ++nt) {
      int l = w * 64 + nt * 16 + l16;
      #pragma unroll
      for (int r = 0; r < 4; ++r) {
        int h = kg * 4 + r;
        acc_part[(base + h) * LOW_ + l] = (unsigned short)f2bf_s(oa[nt][r]);
      }
    }
  }
}

// Fused combine + project (unchanged). grid (16,8,8) x 128 thr.
__global__ __launch_bounds__(128) void reduce_proj_kernel(
    const float* __restrict__ m_part, const float* __restrict__ l_part,
    const unsigned short* __restrict__ acc_part, const float* __restrict__ FU,
    float* __restrict__ o_heads)
{
  int h = blockIdx.x, b = blockIdx.y, lz = blockIdx.z, t = threadIdx.x;
  __shared__ float wls[NCH];
  __shared__ float Linv_s;
  __shared__ float pa0[128], pa1[128];
  __shared__ float wl_sh[64];
  if (t < 64) {
    float mc = m_part[(b * NCH + t) * H_ + h];
    float M = mc;
    #pragma unroll
    for (int d = 1; d < 64; d <<= 1) M = fmaxf(M, __shfl_xor(M, d));
    float wc = expf(mc - M);
    float L = l_part[(b * NCH + t) * H_ + h] * wc;
    #pragma unroll
    for (int d = 1; d < 64; d <<= 1) L += __shfl_xor(L, d);
    wls[t] = wc;
    if (t == 0) Linv_s = 1.0f / L;
  }
  __syncthreads();
  {
    int p = t & 31, ch = t >> 5;
    int l0 = lz * 64 + p * 2;
    float a0 = 0.f, a1 = 0.f;
    const unsigned short* ap =
        acc_part + ((size_t)(b * NCH + ch * 16) * H_ + h) * LOW_ + l0;
    #pragma unroll 4
    for (int c = 0; c < 16; ++c) {
      unsigned pk = *(const unsigned*)(ap + (size_t)c * H_ * LOW_);
      float wc = wls[ch * 16 + c];
      a0 = fmaf(bf2f((unsigned short)(pk & 0xffffu)), wc, a0);
      a1 = fmaf(bf2f((unsigned short)(pk >> 16)),     wc, a1);
    }
    pa0[t] = a0; pa1[t] = a1;
  }
  __syncthreads();
  if (t < 32) {
    float inv = Linv_s;
    float s0 = pa0[t] + pa0[t + 32] + pa0[t + 64] + pa0[t + 96];
    float s1 = pa1[t] + pa1[t + 32] + pa1[t + 64] + pa1[t + 96];
    wl_sh[t * 2]     = s0 * inv;
    wl_sh[t * 2 + 1] = s1 * inv;
  }
  __syncthreads();
  {
    float a = 0.f;
    const float* fp = FU + (size_t)(lz * 64) * (2 * E_) + E_ + h * HD_ + t;
    #pragma unroll 4
    for (int l = 0; l < 64; ++l)
      a = fmaf(wl_sh[l], fp[(size_t)l * (2 * E_)], a);
    atomicAdd(&o_heads[(b * H_ + h) * HD_ + t], a);
  }
}

extern "C" void kernel_launch(void* const* d_in, const int* in_sizes, int n_in,
                              void* d_out, int out_size, void* d_ws, size_t ws_size,
                              hipStream_t stream)
{
  const float* x    = (const float*)d_in[0];
  const float* ckvc = (const float*)d_in[1];
  const float* krc  = (const float*)d_in[2];
  const float* Wdq  = (const float*)d_in[3];
  const float* Wuq  = (const float*)d_in[4];
  const float* Wqr  = (const float*)d_in[5];
  const float* Wdkv = (const float*)d_in[6];
  const float* Wkr  = (const float*)d_in[7];
  const float* FU   = (const float*)d_in[8];
  const float* Wo   = (const float*)d_in[9];
  float* out = (float*)d_out;

  char* ws = (char*)d_ws;
  // zeroed prefix (55296 floats):
  float* Cq             = (float*)(ws + 0);        // 65536 B
  float* Qc             = (float*)(ws + 65536);    // 65536 B
  float* qr_pre         = (float*)(ws + 131072);   // 4096 B
  float* ckvn           = (float*)(ws + 135168);   // 16384 B
  float* krn            = (float*)(ws + 151552);   // 4096 B
  float* o_heads        = (float*)(ws + 155648);   // 65536 B  [prefix end 221184]
  unsigned short* qeff  = (unsigned short*)(ws + 221184);  // 131072 B
  float* m_part         = (float*)(ws + 352256);   // 32768 B
  float* l_part         = (float*)(ws + 385024);   // 32768 B
  unsigned short* accp  = (unsigned short*)(ws + 417792);  // 8388608 B (~8.8 MB)

  // Zero all atomic targets
  init_kernel<<<280, 256, 0, stream>>>((float*)ws, out);

  // Cq = x@Wdq ; ckv_new = x@Wdkv ; kr_new = x@Wkr (no prefetch here)
  matvec8<<<dim3(21, 64), 128, 0, stream>>>(x, E_, Wdq, E_, Cq,
                                            Wdkv, LOW_, ckvn, Wkr, HD_, krn,
                                            (const float*)nullptr, 0, 0, 1);
  // Qc = Cq@Wuq ; qr_pre = Cq@Wqr  + prefetch ckv first half (17 pf x-slots)
  matvec8<<<dim3(34, 64), 128, 0, stream>>>(Cq, E_, Wuq, E_, Qc,
                                            Wqr, HD_, qr_pre,
                                            (const float*)nullptr, 0, (float*)nullptr,
                                            ckvc, 0, CKV4_H, 1088);
  // qeff + prefetch ckv second half (64 pf x-slots)
  qeff_kernel<<<dim3(128, 8), 256, 0, stream>>>(Qc, FU, qeff,
                                                ckvc, CKV4_H, CKV4_H);
  attn_kernel<<<dim3(64, 8), 512, 0, stream>>>(ckvc, ckvn, qeff, krc, krn,
                                               qr_pre, accp, m_part, l_part);
  reduce_proj_kernel<<<dim3(16, 8, 8), 128, 0, stream>>>(m_part, l_part, accp,
                                                         FU, o_heads);
  // out = o_heads @ Wo
  matvec8<<<dim3(16, 64), 128, 0, stream>>>(o_heads, E_, Wo, E_, out,
                                            (const float*)nullptr, 0, (float*)nullptr,
                                            (const float*)nullptr, 0, (float*)nullptr,
                                            (const float*)nullptr, 0, 0, 1);
}

// Round 23
// 84.818 us; speedup vs baseline: 1.8103x; 1.0136x over previous
//
#include <hip/hip_runtime.h>
#include <hip/hip_bf16.h>

#define B_ 8
#define SPREV 4095
#define S_ 4096
#define E_ 2048
#define H_ 16
#define HD_ 128
#define LOW_ 512
#define NCH 64      // attention s-chunks per batch
#define CHK 64      // positions per chunk
#define L2INV 0.207620506f   // log2(10000)/64
#define CKV_CH 2096640       // total 8-elem chunks in ckv_cache (8*4095*512/8)
#define CKV_CH_H 1048320     // half

typedef short s8v __attribute__((ext_vector_type(8)));
typedef float f4v __attribute__((ext_vector_type(4)));

__device__ __forceinline__ short f2bf_s(float f) {
  return (short)__bfloat16_as_ushort(__float2bfloat16(f));
}
__device__ __forceinline__ float bf2f(unsigned short h) {
  union { unsigned u; float f; } v; v.u = ((unsigned)h) << 16;
  return v.f;
}
__device__ __forceinline__ void cvt8_store(const float* src, short* dst) {
  f4v a0 = *(const f4v*)src;
  f4v a1 = *(const f4v*)(src + 4);
  s8v bv;
  bv[0]=f2bf_s(a0[0]); bv[1]=f2bf_s(a0[1]); bv[2]=f2bf_s(a0[2]); bv[3]=f2bf_s(a0[3]);
  bv[4]=f2bf_s(a1[0]); bv[5]=f2bf_s(a1[1]); bv[6]=f2bf_s(a1[2]); bv[7]=f2bf_s(a1[3]);
  *(s8v*)dst = bv;
}

// Zero all accumulation targets (55296 ws floats + 16384 out floats).
__global__ __launch_bounds__(256) void init_kernel(float* __restrict__ ws_pre,
                                                   float* __restrict__ out) {
  int i = blockIdx.x * 256 + threadIdx.x;
  if (i < 55296) ws_pre[i] = 0.f;           // Cq,Qc,qr_pre,ckvn,krn,o_heads
  else if (i < 71680) out[i - 55296] = 0.f;
}

// out[b][n] += sum_k x[b][k] * W[k][n], k in [k0, k0+32). Blocks past the
// real column-blocks stream-convert ckv f32 -> bf16 (also warms L3 for attn).
__global__ __launch_bounds__(128) void matvec8(
    const float* __restrict__ x, int K,
    const float* __restrict__ W0, int N0, float* __restrict__ o0,
    const float* __restrict__ W1, int N1, float* __restrict__ o1,
    const float* __restrict__ W2, int N2, float* __restrict__ o2,
    const float* __restrict__ cf32, short* __restrict__ c16,
    int cv_base, int cv_n, int cv_nb)
{
  int cb = blockIdx.x;
  int nb0 = N0 >> 7, nb1 = N1 >> 7, nb2 = N2 >> 7;
  int nbsum = nb0 + nb1 + nb2;
  if (cb >= nbsum) { // ---- convert family: 8 f32 -> 8 bf16 per chunk ----
    int seg = (cb - nbsum) * gridDim.y + blockIdx.y;
    int ftid = seg * 128 + threadIdx.x;
    for (int i = cv_base + ftid; i < cv_base + cv_n; i += cv_nb * 128)
      cvt8_store(cf32 + (size_t)i * 8, c16 + (size_t)i * 8);
    return;
  }
  const float* W; float* o; int N, colbase;
  if (cb < nb0)            { W = W0; o = o0; N = N0; colbase = cb << 7; }
  else if (cb < nb0 + nb1) { W = W1; o = o1; N = N1; colbase = (cb - nb0) << 7; }
  else                     { W = W2; o = o2; N = N2; colbase = (cb - nb0 - nb1) << 7; }
  int col = colbase + threadIdx.x;
  int k0 = blockIdx.y * 32;
  float acc[B_];
  #pragma unroll
  for (int b = 0; b < B_; ++b) acc[b] = 0.f;
  const float* Wp = W + (size_t)k0 * N + col;
  #pragma unroll 8
  for (int k = 0; k < 32; ++k) {
    float wv = Wp[(size_t)k * N];
    #pragma unroll
    for (int b = 0; b < B_; ++b)
      acc[b] = fmaf(x[b * K + k0 + k], wv, acc[b]);   // uniform -> s_load
  }
  #pragma unroll
  for (int b = 0; b < B_; ++b) atomicAdd(&o[b * N + col], acc[b]);
}

// qeff[b,h,l] = sum_d FU[l, h*128+d] * Qc[b, h*128+d]; grid (128, 8) x 256.
// Blocks bx>=64 convert the second half of ckv (+ ckvn) to bf16.
__global__ __launch_bounds__(256) void qeff_kernel(
    const float* __restrict__ Qc, const float* __restrict__ FU,
    unsigned short* __restrict__ qeff,
    const float* __restrict__ cf32, short* __restrict__ c16,
    const float* __restrict__ ckvn, short* __restrict__ ckvn16)
{
  int bx = blockIdx.x, b = blockIdx.y, t = threadIdx.x;
  if (bx >= 64) { // ---- convert family: 64 x-slots x 8 y = 512 blocks ----
    int seg = (bx - 64) * 8 + b;
    if (seg == 0) { // ckvn (8x512 f32) -> bf16: 512 chunks, 2 per thread
      cvt8_store(ckvn + (size_t)t * 8,        ckvn16 + (size_t)t * 8);
      cvt8_store(ckvn + (size_t)(t + 256) * 8, ckvn16 + (size_t)(t + 256) * 8);
    }
    int ftid = seg * 256 + t;
    for (int i = CKV_CH_H + ftid; i < CKV_CH; i += 512 * 256)
      cvt8_store(cf32 + (size_t)i * 8, c16 + (size_t)i * 8);
    return;
  }
  int h = bx >> 2, lq = bx & 3;
  int g = t >> 4, li = t & 15;
  __shared__ float qs[HD_];
  if (t < 128) qs[t] = Qc[b * E_ + h * HD_ + t];
  __syncthreads();
  f4v q0 = *(const f4v*)&qs[li * 8];
  f4v q1 = *(const f4v*)&qs[li * 8 + 4];
  #pragma unroll 2
  for (int p = 0; p < 8; ++p) {
    int l = lq * 128 + p * 16 + g;
    const f4v* w4 = (const f4v*)(FU + (size_t)l * (2 * E_) + h * HD_ + li * 8);
    f4v w0 = w4[0], w1 = w4[1];
    float a = w0[0]*q0[0] + w0[1]*q0[1] + w0[2]*q0[2] + w0[3]*q0[3]
            + w1[0]*q1[0] + w1[1]*q1[1] + w1[2]*q1[2] + w1[3]*q1[3];
    a += __shfl_xor(a, 1); a += __shfl_xor(a, 2);
    a += __shfl_xor(a, 4); a += __shfl_xor(a, 8);
    if (li == 0) qeff[(size_t)(b * H_ + h) * LOW_ + l] = (unsigned short)f2bf_s(a);
  }
}

// Flash-decode over the bf16 ckv copy (L3-hot). 8 waves, r17 structure.
// Phase A: b128 granule loads, no cvt. Phase C: scalar u16 loads, no cvt.
__global__ __launch_bounds__(512) void attn_kernel(
    const short* __restrict__ ckv16, const short* __restrict__ ckvn16,
    const unsigned short* __restrict__ qeff,
    const float* __restrict__ kr_cache, const float* __restrict__ kr_new,
    const float* __restrict__ qr_pre,
    unsigned short* __restrict__ acc_part, float* __restrict__ m_part,
    float* __restrict__ l_part)
{
  int chunk = blockIdx.x, b = blockIdx.y;
  int tid = threadIdx.x;
  int w = tid >> 6, lane = tid & 63;
  int kg = lane >> 4, l16 = lane & 15;
  __shared__ float S_lds[2][16 * 64];       // [k-half][h*64 + (s ^ ((h&7)<<2))]
  __shared__ unsigned short P_lds[16 * 64]; // swizzled: h*64 + (s ^ ((h&7)<<3))
  __shared__ float qr_sh[128];
  __shared__ float rope_lds[64];

  if (tid < 64) {
    float invf = exp2f(-L2INV * (float)tid);
    float x1 = qr_pre[b * HD_ + tid], x2 = qr_pre[b * HD_ + 64 + tid];
    float sn, cs; sincosf(4095.0f * invf, &sn, &cs);
    qr_sh[tid]      = x1 * cs - x2 * sn;
    qr_sh[64 + tid] = x1 * sn + x2 * cs;
  }
  __syncthreads();

  { // ---- phase A: all 8 waves; k-split; bf16 b128 fragments ----
    int kh = w >> 2;
    int s_loc = (w & 3) * 16 + l16;
    int s = chunk * CHK + s_loc;
    const short* crow = (s == S_ - 1) ? (ckvn16 + b * LOW_)
                                      : (ckv16 + ((size_t)b * SPREV + s) * LOW_);
    f4v acc0 = {0.f, 0.f, 0.f, 0.f};
    f4v acc1 = {0.f, 0.f, 0.f, 0.f};
    const s8v* qf = (const s8v*)(qeff + (size_t)(b * H_ + l16) * LOW_);
    #pragma unroll
    for (int bt = 0; bt < 2; ++bt) {
      s8v bvv[4], aq[4];
      #pragma unroll
      for (int u = 0; u < 4; ++u) {
        int kk = kh * 8 + bt * 4 + u;
        bvv[u] = *(const s8v*)(crow + kk * 32 + kg * 8);
        aq[u]  = qf[kk * 4 + kg];
      }
      #pragma unroll
      for (int u = 0; u < 4; ++u) {
        if (u & 1)
          acc1 = __builtin_amdgcn_mfma_f32_16x16x32_bf16(aq[u], bvv[u], acc1, 0, 0, 0);
        else
          acc0 = __builtin_amdgcn_mfma_f32_16x16x32_bf16(aq[u], bvv[u], acc0, 0, 0, 0);
      }
    }
    #pragma unroll
    for (int r = 0; r < 4; ++r) {
      int h = kg * 4 + r;
      S_lds[kh][h * 64 + (s_loc ^ ((h & 7) << 2))] = acc0[r] + acc1[r];
    }
    if (w < 4) {
      const float* krp = (s == S_ - 1) ? (kr_new + b * HD_)
                                       : (kr_cache + ((size_t)b * SPREV + s) * HD_);
      float fs = (float)s;
      float rdot = 0.f;
      #pragma unroll
      for (int q = 0; q < 4; ++q) {
        int j = kg * 16 + q * 4;
        f4v x1 = *(const f4v*)&krp[j];
        f4v x2 = *(const f4v*)&krp[64 + j];
        f4v qa = *(const f4v*)&qr_sh[j];
        f4v qb = *(const f4v*)&qr_sh[64 + j];
        #pragma unroll
        for (int k2 = 0; k2 < 4; ++k2) {
          float invf = exp2f(-L2INV * (float)(j + k2));
          float sn, cs; sincosf(fs * invf, &sn, &cs);
          rdot += qa[k2] * (x1[k2] * cs - x2[k2] * sn)
                + qb[k2] * (x1[k2] * sn + x2[k2] * cs);
        }
      }
      rdot += __shfl_xor(rdot, 16);
      rdot += __shfl_xor(rdot, 32);
      if (kg == 0) rope_lds[s_loc] = rdot;
    }
  }
  __syncthreads();

  { // ---- phase B: all 8 waves; wave w owns h = 2w + (lane>>5), 2 s/lane ----
    int half = lane >> 5;
    int h = w * 2 + half;
    int sl = lane & 31;
    int s0 = sl * 2;
    int c2 = (h & 7) << 2;
    float v0 = (S_lds[0][h * 64 + (s0 ^ c2)] + S_lds[1][h * 64 + (s0 ^ c2)]
                + rope_lds[s0]) * 0.0625f;
    float v1 = (S_lds[0][h * 64 + ((s0 + 1) ^ c2)] + S_lds[1][h * 64 + ((s0 + 1) ^ c2)]
                + rope_lds[s0 + 1]) * 0.0625f;
    float m = fmaxf(v0, v1);
    m = fmaxf(m, __shfl_xor(m, 1));  m = fmaxf(m, __shfl_xor(m, 2));
    m = fmaxf(m, __shfl_xor(m, 4));  m = fmaxf(m, __shfl_xor(m, 8));
    m = fmaxf(m, __shfl_xor(m, 16));
    float e0 = expf(v0 - m), e1 = expf(v1 - m);
    float lsum = e0 + e1;
    lsum += __shfl_xor(lsum, 1);  lsum += __shfl_xor(lsum, 2);
    lsum += __shfl_xor(lsum, 4);  lsum += __shfl_xor(lsum, 8);
    lsum += __shfl_xor(lsum, 16);
    unsigned pk = (unsigned)(unsigned short)f2bf_s(e0) |
                  ((unsigned)(unsigned short)f2bf_s(e1) << 16);
    *(unsigned*)&P_lds[h * 64 + (s0 ^ ((h & 7) << 3))] = pk;
    if (sl == 0) {
      int idx = (b * NCH + chunk) * H_ + h;
      m_part[idx] = m;
      l_part[idx] = lsum;
    }
  }
  __syncthreads();

  { // ---- phase C: wave w owns l in [w*64, w*64+64); bf16 scalar reads ----
    s8v pa[2];
    const short* rp[2][8];
    #pragma unroll
    for (int kt = 0; kt < 2; ++kt) {
      int so = kt * 32 + kg * 8;
      pa[kt] = *(const s8v*)&P_lds[l16 * 64 + (so ^ ((l16 & 7) << 3))];
      #pragma unroll
      for (int i = 0; i < 8; ++i) {
        int s = chunk * CHK + so + i;
        rp[kt][i] = (s == S_ - 1) ? (ckvn16 + b * LOW_)
                                  : (ckv16 + ((size_t)b * SPREV + s) * LOW_);
      }
    }
    f4v oa[4];
    #pragma unroll
    for (int nt = 0; nt < 4; ++nt) oa[nt] = {0.f, 0.f, 0.f, 0.f};
    #pragma unroll
    for (int nt = 0; nt < 4; ++nt) {
      int l = w * 64 + nt * 16 + l16;
      s8v bv0, bv1;
      #pragma unroll
      for (int i = 0; i < 8; ++i) { bv0[i] = rp[0][i][l]; bv1[i] = rp[1][i][l]; }
      oa[nt] = __builtin_amdgcn_mfma_f32_16x16x32_bf16(pa[0], bv0, oa[nt], 0, 0, 0);
      oa[nt] = __builtin_amdgcn_mfma_f32_16x16x32_bf16(pa[1], bv1, oa[nt], 0, 0, 0);
    }
    size_t base = (size_t)(b * NCH + chunk) * H_;
    #pragma unroll
    for (int nt = 0; nt < 4; ++nt) {
      int l = w * 64 + nt * 16 + l16;
      #pragma unroll
      for (int r = 0; r < 4; ++r) {
        int h = kg * 4 + r;
        acc_part[(base + h) * LOW_ + l] = (unsigned short)f2bf_s(oa[nt][r]);
      }
    }
  }
}

// Fused combine + project (unchanged). grid (16,8,8) x 128 thr.
__global__ __launch_bounds__(128) void reduce_proj_kernel(
    const float* __restrict__ m_part, const float* __restrict__ l_part,
    const unsigned short* __restrict__ acc_part, const float* __restrict__ FU,
    float* __restrict__ o_heads)
{
  int h = blockIdx.x, b = blockIdx.y, lz = blockIdx.z, t = threadIdx.x;
  __shared__ float wls[NCH];
  __shared__ float Linv_s;
  __shared__ float pa0[128], pa1[128];
  __shared__ float wl_sh[64];
  if (t < 64) {
    float mc = m_part[(b * NCH + t) * H_ + h];
    float M = mc;
    #pragma unroll
    for (int d = 1; d < 64; d <<= 1) M = fmaxf(M, __shfl_xor(M, d));
    float wc = expf(mc - M);
    float L = l_part[(b * NCH + t) * H_ + h] * wc;
    #pragma unroll
    for (int d = 1; d < 64; d <<= 1) L += __shfl_xor(L, d);
    wls[t] = wc;
    if (t == 0) Linv_s = 1.0f / L;
  }
  __syncthreads();
  {
    int p = t & 31, ch = t >> 5;
    int l0 = lz * 64 + p * 2;
    float a0 = 0.f, a1 = 0.f;
    const unsigned short* ap =
        acc_part + ((size_t)(b * NCH + ch * 16) * H_ + h) * LOW_ + l0;
    #pragma unroll 4
    for (int c = 0; c < 16; ++c) {
      unsigned pk = *(const unsigned*)(ap + (size_t)c * H_ * LOW_);
      float wc = wls[ch * 16 + c];
      a0 = fmaf(bf2f((unsigned short)(pk & 0xffffu)), wc, a0);
      a1 = fmaf(bf2f((unsigned short)(pk >> 16)),     wc, a1);
    }
    pa0[t] = a0; pa1[t] = a1;
  }
  __syncthreads();
  if (t < 32) {
    float inv = Linv_s;
    float s0 = pa0[t] + pa0[t + 32] + pa0[t + 64] + pa0[t + 96];
    float s1 = pa1[t] + pa1[t + 32] + pa1[t + 64] + pa1[t + 96];
    wl_sh[t * 2]     = s0 * inv;
    wl_sh[t * 2 + 1] = s1 * inv;
  }
  __syncthreads();
  {
    float a = 0.f;
    const float* fp = FU + (size_t)(lz * 64) * (2 * E_) + E_ + h * HD_ + t;
    #pragma unroll 4
    for (int l = 0; l < 64; ++l)
      a = fmaf(wl_sh[l], fp[(size_t)l * (2 * E_)], a);
    atomicAdd(&o_heads[(b * H_ + h) * HD_ + t], a);
  }
}

extern "C" void kernel_launch(void* const* d_in, const int* in_sizes, int n_in,
                              void* d_out, int out_size, void* d_ws, size_t ws_size,
                              hipStream_t stream)
{
  const float* x    = (const float*)d_in[0];
  const float* ckvc = (const float*)d_in[1];
  const float* krc  = (const float*)d_in[2];
  const float* Wdq  = (const float*)d_in[3];
  const float* Wuq  = (const float*)d_in[4];
  const float* Wqr  = (const float*)d_in[5];
  const float* Wdkv = (const float*)d_in[6];
  const float* Wkr  = (const float*)d_in[7];
  const float* FU   = (const float*)d_in[8];
  const float* Wo   = (const float*)d_in[9];
  float* out = (float*)d_out;

  char* ws = (char*)d_ws;
  // zeroed prefix (55296 floats):
  float* Cq             = (float*)(ws + 0);        // 65536 B
  float* Qc             = (float*)(ws + 65536);    // 65536 B
  float* qr_pre         = (float*)(ws + 131072);   // 4096 B
  float* ckvn           = (float*)(ws + 135168);   // 16384 B
  float* krn            = (float*)(ws + 151552);   // 4096 B
  float* o_heads        = (float*)(ws + 155648);   // 65536 B  [prefix end 221184]
  unsigned short* qeff  = (unsigned short*)(ws + 221184);  // 131072 B
  float* m_part         = (float*)(ws + 352256);   // 32768 B
  float* l_part         = (float*)(ws + 385024);   // 32768 B
  unsigned short* accp  = (unsigned short*)(ws + 417792);  // 8388608 B
  short* ckv16          = (short*)(ws + 8806400);  // 33546240 B
  short* ckvn16         = (short*)(ws + 42352640); // 8192 B (~42.4 MB total)

  // Zero all atomic targets
  init_kernel<<<280, 256, 0, stream>>>((float*)ws, out);

  // Cq = x@Wdq ; ckv_new = x@Wdkv ; kr_new = x@Wkr (no convert family)
  matvec8<<<dim3(21, 64), 128, 0, stream>>>(x, E_, Wdq, E_, Cq,
                                            Wdkv, LOW_, ckvn, Wkr, HD_, krn,
                                            (const float*)nullptr, (short*)nullptr,
                                            0, 0, 1);
  // Qc = Cq@Wuq ; qr_pre = Cq@Wqr  + convert ckv first half (17 extra x-slots)
  matvec8<<<dim3(34, 64), 128, 0, stream>>>(Cq, E_, Wuq, E_, Qc,
                                            Wqr, HD_, qr_pre,
                                            (const float*)nullptr, 0, (float*)nullptr,
                                            ckvc, ckv16, 0, CKV_CH_H, 1088);
  // qeff + convert ckv second half + ckvn (64 extra x-slots)
  qeff_kernel<<<dim3(128, 8), 256, 0, stream>>>(Qc, FU, qeff,
                                                ckvc, ckv16, ckvn, ckvn16);
  attn_kernel<<<dim3(64, 8), 512, 0, stream>>>(ckv16, ckvn16, qeff, krc, krn,
                                               qr_pre, accp, m_part, l_part);
  reduce_proj_kernel<<<dim3(16, 8, 8), 128, 0, stream>>>(m_part, l_part, accp,
                                                         FU, o_heads);
  // out = o_heads @ Wo
  matvec8<<<dim3(16, 64), 128, 0, stream>>>(o_heads, E_, Wo, E_, out,
                                            (const float*)nullptr, 0, (float*)nullptr,
                                            (const float*)nullptr, 0, (float*)nullptr,
                                            (const float*)nullptr, (short*)nullptr,
                                            0, 0, 1);
}

// Round 24
// 82.671 us; speedup vs baseline: 1.8573x; 1.0260x over previous
//
#include <hip/hip_runtime.h>
#include <hip/hip_bf16.h>

#define B_ 8
#define SPREV 4095
#define S_ 4096
#define E_ 2048
#define H_ 16
#define HD_ 128
#define LOW_ 512
#define NCH 64      // attention s-chunks per batch
#define CHK 64      // positions per chunk
#define L2INV 0.207620506f   // log2(10000)/64

typedef short s8v __attribute__((ext_vector_type(8)));
typedef float f4v __attribute__((ext_vector_type(4)));

__device__ __forceinline__ short f2bf_s(float f) {
  return (short)__bfloat16_as_ushort(__float2bfloat16(f));
}
__device__ __forceinline__ float bf2f(unsigned short h) {
  union { unsigned u; float f; } v; v.u = ((unsigned)h) << 16;
  return v.f;
}

// Zero all accumulation targets (55296 ws floats + 16384 out floats).
__global__ __launch_bounds__(256) void init_kernel(float* __restrict__ ws_pre,
                                                   float* __restrict__ out) {
  int i = blockIdx.x * 256 + threadIdx.x;
  if (i < 55296) ws_pre[i] = 0.f;           // Cq,Qc,qr_pre,ckvn,krn,o_heads
  else if (i < 71680) out[i - 55296] = 0.f;
}

// out[b][n] += sum_k x[b][k] * W[k][n], k in [k0, k0+32).
__global__ __launch_bounds__(128) void matvec8(
    const float* __restrict__ x, int K,
    const float* __restrict__ W0, int N0, float* __restrict__ o0,
    const float* __restrict__ W1, int N1, float* __restrict__ o1,
    const float* __restrict__ W2, int N2, float* __restrict__ o2)
{
  int cb = blockIdx.x;
  int nb0 = N0 >> 7, nb1 = N1 >> 7;
  const float* W; float* o; int N, colbase;
  if (cb < nb0)            { W = W0; o = o0; N = N0; colbase = cb << 7; }
  else if (cb < nb0 + nb1) { W = W1; o = o1; N = N1; colbase = (cb - nb0) << 7; }
  else                     { W = W2; o = o2; N = N2; colbase = (cb - nb0 - nb1) << 7; }
  int col = colbase + threadIdx.x;
  int k0 = blockIdx.y * 32;
  float acc[B_];
  #pragma unroll
  for (int b = 0; b < B_; ++b) acc[b] = 0.f;
  const float* Wp = W + (size_t)k0 * N + col;
  #pragma unroll 8
  for (int k = 0; k < 32; ++k) {
    float wv = Wp[(size_t)k * N];
    #pragma unroll
    for (int b = 0; b < B_; ++b)
      acc[b] = fmaf(x[b * K + k0 + k], wv, acc[b]);   // uniform -> s_load
  }
  #pragma unroll
  for (int b = 0; b < B_; ++b) atomicAdd(&o[b * N + col], acc[b]);
}

// qeff[b,h,l] = sum_d FU[l, h*128+d] * Qc[b, h*128+d]; grid (64, 8) x 256.
__global__ __launch_bounds__(256) void qeff_kernel(
    const float* __restrict__ Qc, const float* __restrict__ FU,
    unsigned short* __restrict__ qeff)
{
  int bx = blockIdx.x, b = blockIdx.y, t = threadIdx.x;
  int h = bx >> 2, lq = bx & 3;
  int g = t >> 4, li = t & 15;
  __shared__ float qs[HD_];
  if (t < 128) qs[t] = Qc[b * E_ + h * HD_ + t];
  __syncthreads();
  f4v q0 = *(const f4v*)&qs[li * 8];
  f4v q1 = *(const f4v*)&qs[li * 8 + 4];
  #pragma unroll 2
  for (int p = 0; p < 8; ++p) {
    int l = lq * 128 + p * 16 + g;
    const f4v* w4 = (const f4v*)(FU + (size_t)l * (2 * E_) + h * HD_ + li * 8);
    f4v w0 = w4[0], w1 = w4[1];
    float a = w0[0]*q0[0] + w0[1]*q0[1] + w0[2]*q0[2] + w0[3]*q0[3]
            + w1[0]*q1[0] + w1[1]*q1[1] + w1[2]*q1[2] + w1[3]*q1[3];
    a += __shfl_xor(a, 1); a += __shfl_xor(a, 2);
    a += __shfl_xor(a, 4); a += __shfl_xor(a, 8);
    if (li == 0) qeff[(size_t)(b * H_ + h) * LOW_ + l] = (unsigned short)f2bf_s(a);
  }
}

// Flash-decode, one (b, 64-chunk) per block, 8 waves (512 thr).
// Phase A: k-split, batch-prefetched loads. Phase B: all-wave softmax.
// Phase C: PV via MFMA, 16 scalars batch-loaded per nt before cvt.
__global__ __launch_bounds__(512) void attn_kernel(
    const float* __restrict__ ckv_cache, const float* __restrict__ ckv_new,
    const unsigned short* __restrict__ qeff,
    const float* __restrict__ kr_cache, const float* __restrict__ kr_new,
    const float* __restrict__ qr_pre,
    unsigned short* __restrict__ acc_part, float* __restrict__ m_part,
    float* __restrict__ l_part)
{
  int chunk = blockIdx.x, b = blockIdx.y;
  int tid = threadIdx.x;
  int w = tid >> 6, lane = tid & 63;
  int kg = lane >> 4, l16 = lane & 15;
  __shared__ float S_lds[2][16 * 64];       // [k-half][h*64 + (s ^ ((h&7)<<2))]
  __shared__ unsigned short P_lds[16 * 64]; // swizzled: h*64 + (s ^ ((h&7)<<3))
  __shared__ float qr_sh[128];
  __shared__ float rope_lds[64];

  // qr rotated at position 4095 (once per block)
  if (tid < 64) {
    float invf = exp2f(-L2INV * (float)tid);
    float x1 = qr_pre[b * HD_ + tid], x2 = qr_pre[b * HD_ + 64 + tid];
    float sn, cs; sincosf(4095.0f * invf, &sn, &cs);
    qr_sh[tid]      = x1 * cs - x2 * sn;
    qr_sh[64 + tid] = x1 * sn + x2 * cs;
  }
  __syncthreads();

  { // ---- phase A: all 8 waves; k-split + 4-kk register batch prefetch ----
    int kh = w >> 2;                         // k-half: kk in [kh*8, kh*8+8)
    int s_loc = (w & 3) * 16 + l16;
    int s = chunk * CHK + s_loc;
    const float* crow = (s == S_ - 1) ? (ckv_new + b * LOW_)
                                      : (ckv_cache + ((size_t)b * SPREV + s) * LOW_);
    f4v acc0 = {0.f, 0.f, 0.f, 0.f};
    f4v acc1 = {0.f, 0.f, 0.f, 0.f};
    const s8v* qf = (const s8v*)(qeff + (size_t)(b * H_ + l16) * LOW_);
    #pragma unroll
    for (int bt = 0; bt < 2; ++bt) {
      f4v c0_[4], c1_[4];
      s8v aq[4];
      #pragma unroll
      for (int u = 0; u < 4; ++u) {        // issue 8 c-loads + 4 a-loads first
        int kk = kh * 8 + bt * 4 + u;
        const float* cp = crow + kk * 32 + kg * 8;
        c0_[u] = *(const f4v*)cp;
        c1_[u] = *(const f4v*)(cp + 4);
        aq[u] = qf[kk * 4 + kg];
      }
      #pragma unroll
      for (int u = 0; u < 4; ++u) {        // then convert + MFMA
        s8v bv;
        bv[0]=f2bf_s(c0_[u][0]); bv[1]=f2bf_s(c0_[u][1]);
        bv[2]=f2bf_s(c0_[u][2]); bv[3]=f2bf_s(c0_[u][3]);
        bv[4]=f2bf_s(c1_[u][0]); bv[5]=f2bf_s(c1_[u][1]);
        bv[6]=f2bf_s(c1_[u][2]); bv[7]=f2bf_s(c1_[u][3]);
        if (u & 1)
          acc1 = __builtin_amdgcn_mfma_f32_16x16x32_bf16(aq[u], bv, acc1, 0, 0, 0);
        else
          acc0 = __builtin_amdgcn_mfma_f32_16x16x32_bf16(aq[u], bv, acc0, 0, 0, 0);
      }
    }
    #pragma unroll
    for (int r = 0; r < 4; ++r) {
      int h = kg * 4 + r;
      S_lds[kh][h * 64 + (s_loc ^ ((h & 7) << 2))] = acc0[r] + acc1[r];
    }
    if (w < 4) { // rope score for this s: j in [kg*16, kg*16+16), shfl reduce
      const float* krp = (s == S_ - 1) ? (kr_new + b * HD_)
                                       : (kr_cache + ((size_t)b * SPREV + s) * HD_);
      float fs = (float)s;
      float rdot = 0.f;
      #pragma unroll
      for (int q = 0; q < 4; ++q) {
        int j = kg * 16 + q * 4;
        f4v x1 = *(const f4v*)&krp[j];
        f4v x2 = *(const f4v*)&krp[64 + j];
        f4v qa = *(const f4v*)&qr_sh[j];
        f4v qb = *(const f4v*)&qr_sh[64 + j];
        #pragma unroll
        for (int k2 = 0; k2 < 4; ++k2) {
          float invf = exp2f(-L2INV * (float)(j + k2));
          float sn, cs; sincosf(fs * invf, &sn, &cs);
          rdot += qa[k2] * (x1[k2] * cs - x2[k2] * sn)
                + qb[k2] * (x1[k2] * sn + x2[k2] * cs);
        }
      }
      rdot += __shfl_xor(rdot, 16);
      rdot += __shfl_xor(rdot, 32);
      if (kg == 0) rope_lds[s_loc] = rdot;
    }
  }
  __syncthreads();

  { // ---- phase B: all 8 waves; wave w owns h = 2w + (lane>>5), 2 s/lane ----
    int half = lane >> 5;
    int h = w * 2 + half;
    int sl = lane & 31;
    int s0 = sl * 2;
    int c2 = (h & 7) << 2;
    float v0 = (S_lds[0][h * 64 + (s0 ^ c2)] + S_lds[1][h * 64 + (s0 ^ c2)]
                + rope_lds[s0]) * 0.0625f;
    float v1 = (S_lds[0][h * 64 + ((s0 + 1) ^ c2)] + S_lds[1][h * 64 + ((s0 + 1) ^ c2)]
                + rope_lds[s0 + 1]) * 0.0625f;
    float m = fmaxf(v0, v1);
    m = fmaxf(m, __shfl_xor(m, 1));  m = fmaxf(m, __shfl_xor(m, 2));
    m = fmaxf(m, __shfl_xor(m, 4));  m = fmaxf(m, __shfl_xor(m, 8));
    m = fmaxf(m, __shfl_xor(m, 16));
    float e0 = expf(v0 - m), e1 = expf(v1 - m);
    float lsum = e0 + e1;
    lsum += __shfl_xor(lsum, 1);  lsum += __shfl_xor(lsum, 2);
    lsum += __shfl_xor(lsum, 4);  lsum += __shfl_xor(lsum, 8);
    lsum += __shfl_xor(lsum, 16);
    unsigned pk = (unsigned)(unsigned short)f2bf_s(e0) |
                  ((unsigned)(unsigned short)f2bf_s(e1) << 16);
    *(unsigned*)&P_lds[h * 64 + (s0 ^ ((h & 7) << 3))] = pk;
    if (sl == 0) {
      int idx = (b * NCH + chunk) * H_ + h;
      m_part[idx] = m;
      l_part[idx] = lsum;
    }
  }
  __syncthreads();

  { // ---- phase C: wave w owns l in [w*64, w*64+64), batch 16 loads per nt ----
    s8v pa[2];
    const float* rp[2][8];
    #pragma unroll
    for (int kt = 0; kt < 2; ++kt) {
      int so = kt * 32 + kg * 8;
      pa[kt] = *(const s8v*)&P_lds[l16 * 64 + (so ^ ((l16 & 7) << 3))];
      #pragma unroll
      for (int i = 0; i < 8; ++i) {
        int s = chunk * CHK + so + i;
        rp[kt][i] = (s == S_ - 1) ? (ckv_new + b * LOW_)
                                  : (ckv_cache + ((size_t)b * SPREV + s) * LOW_);
      }
    }
    f4v oa[4];
    #pragma unroll
    for (int nt = 0; nt < 4; ++nt) oa[nt] = {0.f, 0.f, 0.f, 0.f};
    #pragma unroll
    for (int nt = 0; nt < 4; ++nt) {
      int l = w * 64 + nt * 16 + l16;
      float vb0[8], vb1[8];
      #pragma unroll
      for (int i = 0; i < 8; ++i) { vb0[i] = rp[0][i][l]; vb1[i] = rp[1][i][l]; }
      s8v bv0, bv1;
      #pragma unroll
      for (int i = 0; i < 8; ++i) {
        bv0[i] = f2bf_s(vb0[i]);
        bv1[i] = f2bf_s(vb1[i]);
      }
      oa[nt] = __builtin_amdgcn_mfma_f32_16x16x32_bf16(pa[0], bv0, oa[nt], 0, 0, 0);
      oa[nt] = __builtin_amdgcn_mfma_f32_16x16x32_bf16(pa[1], bv1, oa[nt], 0, 0, 0);
    }
    size_t base = (size_t)(b * NCH + chunk) * H_;
    #pragma unroll
    for (int nt = 0; nt < 4; ++nt) {
      int l = w * 64 + nt * 16 + l16;
      #pragma unroll
      for (int r = 0; r < 4; ++r) {
        int h = kg * 4 + r;
        acc_part[(base + h) * LOW_ + l] = (unsigned short)f2bf_s(oa[nt][r]);
      }
    }
  }
}

// Fused combine + project. grid (16,8,8) x 128 thr.
__global__ __launch_bounds__(128) void reduce_proj_kernel(
    const float* __restrict__ m_part, const float* __restrict__ l_part,
    const unsigned short* __restrict__ acc_part, const float* __restrict__ FU,
    float* __restrict__ o_heads)
{
  int h = blockIdx.x, b = blockIdx.y, lz = blockIdx.z, t = threadIdx.x;
  __shared__ float wls[NCH];
  __shared__ float Linv_s;
  __shared__ float pa0[128], pa1[128];
  __shared__ float wl_sh[64];
  if (t < 64) {
    float mc = m_part[(b * NCH + t) * H_ + h];
    float M = mc;
    #pragma unroll
    for (int d = 1; d < 64; d <<= 1) M = fmaxf(M, __shfl_xor(M, d));
    float wc = expf(mc - M);
    float L = l_part[(b * NCH + t) * H_ + h] * wc;
    #pragma unroll
    for (int d = 1; d < 64; d <<= 1) L += __shfl_xor(L, d);
    wls[t] = wc;
    if (t == 0) Linv_s = 1.0f / L;
  }
  __syncthreads();
  {
    int p = t & 31, ch = t >> 5;
    int l0 = lz * 64 + p * 2;
    float a0 = 0.f, a1 = 0.f;
    const unsigned short* ap =
        acc_part + ((size_t)(b * NCH + ch * 16) * H_ + h) * LOW_ + l0;
    #pragma unroll 4
    for (int c = 0; c < 16; ++c) {
      unsigned pk = *(const unsigned*)(ap + (size_t)c * H_ * LOW_);
      float wc = wls[ch * 16 + c];
      a0 = fmaf(bf2f((unsigned short)(pk & 0xffffu)), wc, a0);
      a1 = fmaf(bf2f((unsigned short)(pk >> 16)),     wc, a1);
    }
    pa0[t] = a0; pa1[t] = a1;
  }
  __syncthreads();
  if (t < 32) {
    float inv = Linv_s;
    float s0 = pa0[t] + pa0[t + 32] + pa0[t + 64] + pa0[t + 96];
    float s1 = pa1[t] + pa1[t + 32] + pa1[t + 64] + pa1[t + 96];
    wl_sh[t * 2]     = s0 * inv;
    wl_sh[t * 2 + 1] = s1 * inv;
  }
  __syncthreads();
  {
    float a = 0.f;
    const float* fp = FU + (size_t)(lz * 64) * (2 * E_) + E_ + h * HD_ + t;
    #pragma unroll 4
    for (int l = 0; l < 64; ++l)
      a = fmaf(wl_sh[l], fp[(size_t)l * (2 * E_)], a);
    atomicAdd(&o_heads[(b * H_ + h) * HD_ + t], a);
  }
}

extern "C" void kernel_launch(void* const* d_in, const int* in_sizes, int n_in,
                              void* d_out, int out_size, void* d_ws, size_t ws_size,
                              hipStream_t stream)
{
  const float* x    = (const float*)d_in[0];
  const float* ckvc = (const float*)d_in[1];
  const float* krc  = (const float*)d_in[2];
  const float* Wdq  = (const float*)d_in[3];
  const float* Wuq  = (const float*)d_in[4];
  const float* Wqr  = (const float*)d_in[5];
  const float* Wdkv = (const float*)d_in[6];
  const float* Wkr  = (const float*)d_in[7];
  const float* FU   = (const float*)d_in[8];
  const float* Wo   = (const float*)d_in[9];
  float* out = (float*)d_out;

  char* ws = (char*)d_ws;
  // zeroed prefix (55296 floats):
  float* Cq             = (float*)(ws + 0);        // 65536 B
  float* Qc             = (float*)(ws + 65536);    // 65536 B
  float* qr_pre         = (float*)(ws + 131072);   // 4096 B
  float* ckvn           = (float*)(ws + 135168);   // 16384 B
  float* krn            = (float*)(ws + 151552);   // 4096 B
  float* o_heads        = (float*)(ws + 155648);   // 65536 B  [prefix end 221184]
  unsigned short* qeff  = (unsigned short*)(ws + 221184);  // 131072 B
  float* m_part         = (float*)(ws + 352256);   // 32768 B
  float* l_part         = (float*)(ws + 385024);   // 32768 B
  unsigned short* accp  = (unsigned short*)(ws + 417792);  // 8388608 B (~8.8 MB)

  // Zero all atomic targets
  init_kernel<<<280, 256, 0, stream>>>((float*)ws, out);

  // Cq = x@Wdq ; ckv_new = x@Wdkv ; kr_new = x@Wkr
  matvec8<<<dim3(21, 64), 128, 0, stream>>>(x, E_, Wdq, E_, Cq,
                                            Wdkv, LOW_, ckvn, Wkr, HD_, krn);
  // Qc = Cq@Wuq ; qr_pre = Cq@Wqr
  matvec8<<<dim3(17, 64), 128, 0, stream>>>(Cq, E_, Wuq, E_, Qc,
                                            Wqr, HD_, qr_pre,
                                            (const float*)nullptr, 0, (float*)nullptr);
  qeff_kernel<<<dim3(64, 8), 256, 0, stream>>>(Qc, FU, qeff);
  attn_kernel<<<dim3(64, 8), 512, 0, stream>>>(ckvc, ckvn, qeff, krc, krn,
                                               qr_pre, accp, m_part, l_part);
  reduce_proj_kernel<<<dim3(16, 8, 8), 128, 0, stream>>>(m_part, l_part, accp,
                                                         FU, o_heads);
  // out = o_heads @ Wo
  matvec8<<<dim3(16, 64), 128, 0, stream>>>(o_heads, E_, Wo, E_, out,
                                            (const float*)nullptr, 0, (float*)nullptr,
                                            (const float*)nullptr, 0, (float*)nullptr);
}